// Round 2
// baseline (1296.237 us; speedup 1.0000x reference)
//
#include <hip/hip_runtime.h>

// Problem constants (checked against in_sizes at runtime where cheap)
#define IN_F  512
#define HID_F 256
#define OUT_F 128
#define G_STATS 1024   // blocks for stats partial reduction
#define B_COL   512    // blocks for column-sum reduction

// ---------------- graph prep ----------------
__global__ __launch_bounds__(256) void count_kernel(const int* __restrict__ dst, int E,
                                                    int* __restrict__ counts) {
  int stride = gridDim.x * blockDim.x;
  for (int i = blockIdx.x * blockDim.x + threadIdx.x; i < E; i += stride)
    atomicAdd(&counts[dst[i]], 1);
}

__global__ __launch_bounds__(256) void dinv_kernel(const int* __restrict__ counts,
                                                   float* __restrict__ dinv, int n) {
  int i = blockIdx.x * blockDim.x + threadIdx.x;
  if (i < n) dinv[i] = rsqrtf((float)counts[i] + 1.0f);  // +1 self-loop, always > 0
}

// Exclusive scan of counts[n] -> row_ptr[n+1], single block of 1024 threads.
__global__ __launch_bounds__(1024) void scan_kernel(const int* __restrict__ counts,
                                                    int* __restrict__ row_ptr, int n) {
  __shared__ int wsum[16];
  __shared__ int s_carry, s_total;
  const int tid = threadIdx.x;
  const int lane = tid & 63, wid = tid >> 6;
  if (tid == 0) { s_carry = 0; row_ptr[0] = 0; }
  __syncthreads();
  const int PER = 8, CH = 1024 * PER;
  for (int base = 0; base < n; base += CH) {
    int i0 = base + tid * PER;
    int v[PER];
    int s = 0;
#pragma unroll
    for (int j = 0; j < PER; ++j) { int i = i0 + j; int c = (i < n) ? counts[i] : 0; s += c; v[j] = s; }
    // wave-inclusive scan of per-thread totals
    int ts = s;
#pragma unroll
    for (int off = 1; off < 64; off <<= 1) {
      int o = __shfl_up(ts, off, 64);
      if (lane >= off) ts += o;
    }
    if (lane == 63) wsum[wid] = ts;
    __syncthreads();
    if (tid == 0) {
      int c = 0;
#pragma unroll
      for (int w = 0; w < 16; ++w) { int t = wsum[w]; wsum[w] = c; c += t; }
      s_total = c;
    }
    __syncthreads();
    int base_excl = s_carry + wsum[wid] + (ts - s);
#pragma unroll
    for (int j = 0; j < PER; ++j) { int i = i0 + j; if (i < n) row_ptr[i + 1] = base_excl + v[j]; }
    __syncthreads();
    if (tid == 0) s_carry += s_total;
    __syncthreads();
  }
}

__global__ __launch_bounds__(256) void scatter_kernel(const int* __restrict__ src,
                                                      const int* __restrict__ dst, int E,
                                                      const int* __restrict__ row_ptr,
                                                      int* __restrict__ fill,
                                                      int* __restrict__ csr_src) {
  int stride = gridDim.x * blockDim.x;
  for (int i = blockIdx.x * blockDim.x + threadIdx.x; i < E; i += stride) {
    int d = dst[i];
    int p = row_ptr[d] + atomicAdd(&fill[d], 1);
    csr_src[p] = src[i];
  }
}

// ---------------- LN stats ----------------
__global__ __launch_bounds__(256) void stats_partial(const float4* __restrict__ x, long n4,
                                                     double* __restrict__ psum,
                                                     double* __restrict__ psq) {
  double s = 0.0, q = 0.0;
  long stride = (long)gridDim.x * 256;
  for (long i = (long)blockIdx.x * 256 + threadIdx.x; i < n4; i += stride) {
    float4 v = x[i];
    s += (double)((v.x + v.y) + (v.z + v.w));
    q += (double)v.x * v.x + (double)v.y * v.y + (double)v.z * v.z + (double)v.w * v.w;
  }
  __shared__ double sh[256], sh2[256];
  sh[threadIdx.x] = s; sh2[threadIdx.x] = q;
  __syncthreads();
  for (int off = 128; off > 0; off >>= 1) {
    if (threadIdx.x < off) { sh[threadIdx.x] += sh[threadIdx.x + off]; sh2[threadIdx.x] += sh2[threadIdx.x + off]; }
    __syncthreads();
  }
  if (threadIdx.x == 0) { psum[blockIdx.x] = sh[0]; psq[blockIdx.x] = sh2[0]; }
}

// Reduce partials, then write per-channel fused scale/shift: a = x*s[k] + t[k]
__global__ void finalize_ln(const double* __restrict__ psum, const double* __restrict__ psq,
                            int nb, double inv_count,
                            const float* __restrict__ lnw, const float* __restrict__ lnb,
                            float* __restrict__ s, float* __restrict__ t, int C) {
  double a = 0.0, b = 0.0;
  for (int i = threadIdx.x; i < nb; i += blockDim.x) { a += psum[i]; b += psq[i]; }
  __shared__ double sa[512], sb[512];
  sa[threadIdx.x] = a; sb[threadIdx.x] = b;
  __syncthreads();
  for (int off = blockDim.x >> 1; off > 0; off >>= 1) {
    if ((int)threadIdx.x < off) { sa[threadIdx.x] += sa[threadIdx.x + off]; sb[threadIdx.x] += sb[threadIdx.x + off]; }
    __syncthreads();
  }
  double mean = sa[0] * inv_count;
  double var  = sb[0] * inv_count - mean * mean;
  double inv  = 1.0 / sqrt(var + 1e-5);
  int k = threadIdx.x;
  if (k < C) {
    double sc = inv * (double)lnw[k];
    s[k] = (float)sc;
    t[k] = (float)((double)lnb[k] - mean * sc);
  }
}

// ---------------- fp32 GEMM with fused LN on A ----------------
// out[M,N] = LN(X)[M,K] @ W[K,N];  LN fused as x*s[k]+t[k]
#define BM 128
#define BN 128
#define BK 16
__global__ __launch_bounds__(256) void gemm_ln(const float* __restrict__ X, int M, int K, int N,
                                               const float* __restrict__ W,
                                               const float* __restrict__ s,
                                               const float* __restrict__ t,
                                               float* __restrict__ out) {
  __shared__ float As[BK][BM + 4];
  __shared__ float Bs[BK][BN];
  const int bm = blockIdx.x * BM;
  const int bn = blockIdx.y * BN;
  const int tid = threadIdx.x;
  const int tm0 = (tid % 16) * 8;
  const int tn0 = (tid / 16) * 8;
  float acc[8][8];
#pragma unroll
  for (int i = 0; i < 8; ++i)
#pragma unroll
    for (int j = 0; j < 8; ++j) acc[i][j] = 0.0f;

  for (int k0 = 0; k0 < K; k0 += BK) {
#pragma unroll
    for (int l = 0; l < 2; ++l) {  // A tile: 128x16 = 512 float4
      int idx = tid + l * 256;
      int row = idx >> 2;
      int kc = (idx & 3) << 2;
      int gm = bm + row, gk = k0 + kc;
      float4 av = make_float4(0.f, 0.f, 0.f, 0.f);
      if (gm < M) {
        float4 xv = *(const float4*)&X[(size_t)gm * K + gk];
        float4 sv = *(const float4*)&s[gk];
        float4 tv = *(const float4*)&t[gk];
        av.x = fmaf(xv.x, sv.x, tv.x);
        av.y = fmaf(xv.y, sv.y, tv.y);
        av.z = fmaf(xv.z, sv.z, tv.z);
        av.w = fmaf(xv.w, sv.w, tv.w);
      }
      As[kc + 0][row] = av.x;
      As[kc + 1][row] = av.y;
      As[kc + 2][row] = av.z;
      As[kc + 3][row] = av.w;
    }
#pragma unroll
    for (int l = 0; l < 2; ++l) {  // B tile: 16x128 = 512 float4
      int idx = tid + l * 256;
      int row = idx >> 5;
      int c = (idx & 31) << 2;
      *(float4*)&Bs[row][c] = *(const float4*)&W[(size_t)(k0 + row) * N + bn + c];
    }
    __syncthreads();
#pragma unroll
    for (int k = 0; k < BK; ++k) {
      float a[8], b[8];
      *(float4*)&a[0] = *(const float4*)&As[k][tm0];
      *(float4*)&a[4] = *(const float4*)&As[k][tm0 + 4];
      *(float4*)&b[0] = *(const float4*)&Bs[k][tn0];
      *(float4*)&b[4] = *(const float4*)&Bs[k][tn0 + 4];
#pragma unroll
      for (int i = 0; i < 8; ++i)
#pragma unroll
        for (int j = 0; j < 8; ++j) acc[i][j] = fmaf(a[i], b[j], acc[i][j]);
    }
    __syncthreads();
  }
#pragma unroll
  for (int i = 0; i < 8; ++i) {
    int gm = bm + tm0 + i;
    if (gm < M) {
      float4 v0 = make_float4(acc[i][0], acc[i][1], acc[i][2], acc[i][3]);
      float4 v1 = make_float4(acc[i][4], acc[i][5], acc[i][6], acc[i][7]);
      *(float4*)&out[(size_t)gm * N + bn + tn0] = v0;
      *(float4*)&out[(size_t)gm * N + bn + tn0 + 4] = v1;
    }
  }
}

// ---------------- pull aggregation + bias + ReLU ----------------
// out[d] = relu( dinv[d] * ( sum_e dinv[src_e]*H[src_e] + dinv[d]*H[d] ) + bias )
template <int F>
__global__ __launch_bounds__(256) void agg_kernel(const float* __restrict__ H,
                                                  const int* __restrict__ row_ptr,
                                                  const int* __restrict__ csr_src,
                                                  const float* __restrict__ dinv,
                                                  const float* __restrict__ bias,
                                                  float* __restrict__ out, int n) {
  constexpr int NODES = 256 / F;
  int node = blockIdx.x * NODES + threadIdx.x / F;
  int f = threadIdx.x % F;
  if (node >= n) return;
  float di = dinv[node];
  float self = di * H[(size_t)node * F + f];
  int e0 = row_ptr[node], e1 = row_ptr[node + 1];
  float acc0 = 0.f, acc1 = 0.f;
  int e = e0;
  for (; e + 1 < e1; e += 2) {
    int s0 = csr_src[e], s1 = csr_src[e + 1];
    float w0 = dinv[s0], w1 = dinv[s1];
    acc0 = fmaf(w0, H[(size_t)s0 * F + f], acc0);
    acc1 = fmaf(w1, H[(size_t)s1 * F + f], acc1);
  }
  if (e < e1) {
    int s0 = csr_src[e];
    acc0 = fmaf(dinv[s0], H[(size_t)s0 * F + f], acc0);
  }
  float r = fmaf(di, (acc0 + acc1) + self, bias[f]);
  out[(size_t)node * F + f] = fmaxf(r, 0.0f);
}

// ---------------- final LN + mean pool (collapsed) ----------------
__global__ __launch_bounds__(128) void colsum_kernel(const float* __restrict__ c2, int n,
                                                     double* __restrict__ colpart,
                                                     double* __restrict__ qpart) {
  int c = threadIdx.x;
  int b = blockIdx.x, B = gridDim.x;
  int rows_per = (n + B - 1) / B;
  int r0 = b * rows_per, r1 = min(n, r0 + rows_per);
  double s = 0.0, q = 0.0;
  for (int r = r0; r < r1; ++r) {
    float v = c2[(size_t)r * OUT_F + c];
    s += v;
    q += (double)v * v;
  }
  colpart[(size_t)b * OUT_F + c] = s;
  __shared__ double sh[128];
  sh[c] = q;
  __syncthreads();
  for (int off = 64; off > 0; off >>= 1) {
    if (c < off) sh[c] += sh[c + off];
    __syncthreads();
  }
  if (c == 0) qpart[b] = sh[0];
}

__global__ __launch_bounds__(128) void final_kernel(const double* __restrict__ colpart,
                                                    const double* __restrict__ qpart, int B, int n,
                                                    const float* __restrict__ lnw,
                                                    const float* __restrict__ lnb,
                                                    float* __restrict__ out) {
  int c = threadIdx.x;
  double s = 0.0;
  for (int b = 0; b < B; ++b) s += colpart[(size_t)b * OUT_F + c];
  double q = 0.0;
  for (int b = c; b < B; b += 128) q += qpart[b];
  __shared__ double shq[128], shs[128];
  shq[c] = q; shs[c] = s;
  __syncthreads();
  for (int off = 64; off > 0; off >>= 1) {
    if (c < off) { shq[c] += shq[c + off]; shs[c] += shs[c + off]; }
    __syncthreads();
  }
  double cnt = (double)n * (double)OUT_F;
  double mean = shs[0] / cnt;
  double var = shq[0] / cnt - mean * mean;
  double inv = 1.0 / sqrt(var + 1e-5);
  double colmean = s / (double)n;
  out[c] = (float)((colmean - mean) * inv * (double)lnw[c] + (double)lnb[c]);
}

// ---------------- launch ----------------
extern "C" void kernel_launch(void* const* d_in, const int* in_sizes, int n_in,
                              void* d_out, int out_size, void* d_ws, size_t ws_size,
                              hipStream_t stream) {
  const float* x   = (const float*)d_in[0];
  const int*  ei   = (const int*)d_in[1];
  const float* W1  = (const float*)d_in[2];
  const float* b1  = (const float*)d_in[3];
  const float* W2  = (const float*)d_in[4];
  const float* b2  = (const float*)d_in[5];
  const float* ln0w = (const float*)d_in[6];
  const float* ln0b = (const float*)d_in[7];
  const float* ln1w = (const float*)d_in[8];
  const float* ln1b = (const float*)d_in[9];
  const float* ln2w = (const float*)d_in[10];
  const float* ln2b = (const float*)d_in[11];

  const int N = in_sizes[0] / IN_F;
  const int E = in_sizes[1] / 2;
  const int* src = ei;
  const int* dst = ei + E;

  char* ws = (char*)d_ws;
  size_t off = 0;
  auto alloc = [&](size_t bytes) -> void* {
    void* p = ws + off;
    off += (bytes + 255) & ~(size_t)255;
    return p;
  };
  int*    counts  = (int*)alloc((size_t)N * 4);        // zeroed
  int*    fill    = (int*)alloc((size_t)N * 4);        // zeroed
  size_t zero_bytes = off;
  float*  dinv    = (float*)alloc((size_t)N * 4);
  int*    row_ptr = (int*)alloc((size_t)(N + 1) * 4);
  int*    csr_src = (int*)alloc((size_t)E * 4);
  double* psum    = (double*)alloc(G_STATS * 8);
  double* psq     = (double*)alloc(G_STATS * 8);
  double* colpart = (double*)alloc((size_t)B_COL * OUT_F * 8);
  double* qpart   = (double*)alloc((size_t)B_COL * 8);
  float*  s0      = (float*)alloc(IN_F * 4);
  float*  t0      = (float*)alloc(IN_F * 4);
  float*  s1      = (float*)alloc(HID_F * 4);
  float*  t1      = (float*)alloc(HID_F * 4);
  float*  h1      = (float*)alloc((size_t)N * HID_F * 4);  // reused: h2 = h1[0:], c2 = h1[N*OUT_F:]
  float*  c1      = (float*)alloc((size_t)N * HID_F * 4);
  float*  h2 = h1;
  float*  c2 = h1 + (size_t)N * OUT_F;

  hipMemsetAsync(ws, 0, zero_bytes, stream);

  // graph prep
  count_kernel<<<1024, 256, 0, stream>>>(dst, E, counts);
  dinv_kernel<<<(N + 255) / 256, 256, 0, stream>>>(counts, dinv, N);
  scan_kernel<<<1, 1024, 0, stream>>>(counts, row_ptr, N);
  scatter_kernel<<<1024, 256, 0, stream>>>(src, dst, E, row_ptr, fill, csr_src);

  // LN0 stats (over x) -> fused scale/shift
  stats_partial<<<G_STATS, 256, 0, stream>>>((const float4*)x, (long)N * IN_F / 4, psum, psq);
  finalize_ln<<<1, 512, 0, stream>>>(psum, psq, G_STATS, 1.0 / ((double)N * IN_F), ln0w, ln0b, s0, t0, IN_F);

  // conv1: h1 = LN0(x) @ W1 ; agg -> c1 (bias+relu fused)
  dim3 g1((N + BM - 1) / BM, HID_F / BN);
  gemm_ln<<<g1, 256, 0, stream>>>(x, N, IN_F, HID_F, W1, s0, t0, h1);
  agg_kernel<HID_F><<<N, 256, 0, stream>>>(h1, row_ptr, csr_src, dinv, b1, c1, N);

  // LN1 stats (over c1)
  stats_partial<<<G_STATS, 256, 0, stream>>>((const float4*)c1, (long)N * HID_F / 4, psum, psq);
  finalize_ln<<<1, 256, 0, stream>>>(psum, psq, G_STATS, 1.0 / ((double)N * HID_F), ln1w, ln1b, s1, t1, HID_F);

  // conv2: h2 = LN1(c1) @ W2 ; agg -> c2
  dim3 g2((N + BM - 1) / BM, OUT_F / BN);
  gemm_ln<<<g2, 256, 0, stream>>>(c1, N, HID_F, OUT_F, W2, s1, t1, h2);
  agg_kernel<OUT_F><<<(N + 1) / 2, 256, 0, stream>>>(h2, row_ptr, csr_src, dinv, b2, c2, N);

  // final LN + mean pool
  colsum_kernel<<<B_COL, 128, 0, stream>>>(c2, N, colpart, qpart);
  final_kernel<<<1, 128, 0, stream>>>(colpart, qpart, B_COL, N, ln2w, ln2b, (float*)d_out);
}

// Round 3
// 1010.016 us; speedup vs baseline: 1.2834x; 1.2834x over previous
//
#include <hip/hip_runtime.h>

// Problem constants
#define IN_F  512
#define HID_F 256
#define OUT_F 128
#define G_STATS 1024   // blocks for stats partial reduction
#define B_COL   512    // blocks for column-sum reduction

// ---------------- helpers ----------------
__device__ inline unsigned short f2bf_rne(float f) {
  unsigned int u = __float_as_uint(f);
  unsigned int r = (u + 0x7fffu + ((u >> 16) & 1u)) >> 16;
  return (unsigned short)r;
}
__device__ inline unsigned int pack_bf2(float lo, float hi) {
  return (unsigned int)f2bf_rne(lo) | ((unsigned int)f2bf_rne(hi) << 16);
}
__device__ inline float bf_lo(unsigned int u) { return __uint_as_float(u << 16); }
__device__ inline float bf_hi(unsigned int u) { return __uint_as_float(u & 0xffff0000u); }

// ---------------- graph prep ----------------
__global__ __launch_bounds__(256) void count_kernel(const int* __restrict__ dst, int E,
                                                    int* __restrict__ counts) {
  int stride = gridDim.x * blockDim.x;
  for (int i = blockIdx.x * blockDim.x + threadIdx.x; i < E; i += stride)
    atomicAdd(&counts[dst[i]], 1);
}

__global__ __launch_bounds__(256) void dinv_kernel(const int* __restrict__ counts,
                                                   float* __restrict__ dinv, int n) {
  int i = blockIdx.x * blockDim.x + threadIdx.x;
  if (i < n) dinv[i] = rsqrtf((float)counts[i] + 1.0f);  // +1 self-loop, always > 0
}

// Exclusive scan of counts[n] -> row_ptr[n+1], single block of 1024 threads.
__global__ __launch_bounds__(1024) void scan_kernel(const int* __restrict__ counts,
                                                    int* __restrict__ row_ptr, int n) {
  __shared__ int wsum[16];
  __shared__ int s_carry, s_total;
  const int tid = threadIdx.x;
  const int lane = tid & 63, wid = tid >> 6;
  if (tid == 0) { s_carry = 0; row_ptr[0] = 0; }
  __syncthreads();
  const int PER = 8, CH = 1024 * PER;
  for (int base = 0; base < n; base += CH) {
    int i0 = base + tid * PER;
    int v[PER];
    int s = 0;
#pragma unroll
    for (int j = 0; j < PER; ++j) { int i = i0 + j; int c = (i < n) ? counts[i] : 0; s += c; v[j] = s; }
    int ts = s;
#pragma unroll
    for (int off = 1; off < 64; off <<= 1) {
      int o = __shfl_up(ts, off, 64);
      if (lane >= off) ts += o;
    }
    if (lane == 63) wsum[wid] = ts;
    __syncthreads();
    if (tid == 0) {
      int c = 0;
#pragma unroll
      for (int w = 0; w < 16; ++w) { int t = wsum[w]; wsum[w] = c; c += t; }
      s_total = c;
    }
    __syncthreads();
    int base_excl = s_carry + wsum[wid] + (ts - s);
#pragma unroll
    for (int j = 0; j < PER; ++j) { int i = i0 + j; if (i < n) row_ptr[i + 1] = base_excl + v[j]; }
    __syncthreads();
    if (tid == 0) s_carry += s_total;
    __syncthreads();
  }
}

__global__ __launch_bounds__(256) void scatter_kernel(const int* __restrict__ src,
                                                      const int* __restrict__ dst, int E,
                                                      const int* __restrict__ row_ptr,
                                                      int* __restrict__ fill,
                                                      int* __restrict__ csr_src) {
  int stride = gridDim.x * blockDim.x;
  for (int i = blockIdx.x * blockDim.x + threadIdx.x; i < E; i += stride) {
    int d = dst[i];
    int p = row_ptr[d] + atomicAdd(&fill[d], 1);
    csr_src[p] = src[i];
  }
}

// ---------------- LN stats ----------------
__global__ __launch_bounds__(256) void stats_partial(const float4* __restrict__ x, long n4,
                                                     double* __restrict__ psum,
                                                     double* __restrict__ psq) {
  double s = 0.0, q = 0.0;
  long stride = (long)gridDim.x * 256;
  for (long i = (long)blockIdx.x * 256 + threadIdx.x; i < n4; i += stride) {
    float4 v = x[i];
    s += (double)((v.x + v.y) + (v.z + v.w));
    q += (double)v.x * v.x + (double)v.y * v.y + (double)v.z * v.z + (double)v.w * v.w;
  }
  __shared__ double sh[256], sh2[256];
  sh[threadIdx.x] = s; sh2[threadIdx.x] = q;
  __syncthreads();
  for (int off = 128; off > 0; off >>= 1) {
    if (threadIdx.x < off) { sh[threadIdx.x] += sh[threadIdx.x + off]; sh2[threadIdx.x] += sh2[threadIdx.x + off]; }
    __syncthreads();
  }
  if (threadIdx.x == 0) { psum[blockIdx.x] = sh[0]; psq[blockIdx.x] = sh2[0]; }
}

// Reduce partials, then write per-channel fused scale/shift: a = x*s[k] + t[k]
__global__ void finalize_ln(const double* __restrict__ psum, const double* __restrict__ psq,
                            int nb, double inv_count,
                            const float* __restrict__ lnw, const float* __restrict__ lnb,
                            float* __restrict__ s, float* __restrict__ t, int C) {
  double a = 0.0, b = 0.0;
  for (int i = threadIdx.x; i < nb; i += blockDim.x) { a += psum[i]; b += psq[i]; }
  __shared__ double sa[512], sb[512];
  sa[threadIdx.x] = a; sb[threadIdx.x] = b;
  __syncthreads();
  for (int off = blockDim.x >> 1; off > 0; off >>= 1) {
    if ((int)threadIdx.x < off) { sa[threadIdx.x] += sa[threadIdx.x + off]; sb[threadIdx.x] += sb[threadIdx.x + off]; }
    __syncthreads();
  }
  double mean = sa[0] * inv_count;
  double var  = sb[0] * inv_count - mean * mean;
  double inv  = 1.0 / sqrt(var + 1e-5);
  int k = threadIdx.x;
  if (k < C) {
    double sc = inv * (double)lnw[k];
    s[k] = (float)sc;
    t[k] = (float)((double)lnb[k] - mean * sc);
  }
}

// ---------------- fp32 GEMM with fused LN on A, dinv-scaled bf16 output ----------------
// outbf[m, :] = bf16( dinv[m] * (LN(X)[m,:K] @ W[K,N]) ), packed 2 bf16 per uint
#define BM 128
#define BN 128
#define BK 16
__global__ __launch_bounds__(256) void gemm_ln(const float* __restrict__ X, int M, int K, int N,
                                               const float* __restrict__ W,
                                               const float* __restrict__ s,
                                               const float* __restrict__ t,
                                               const float* __restrict__ dinv,
                                               unsigned int* __restrict__ outbf) {
  __shared__ float As[BK][BM + 4];
  __shared__ float Bs[BK][BN];
  const int bm = blockIdx.x * BM;
  const int bn = blockIdx.y * BN;
  const int tid = threadIdx.x;
  const int tm0 = (tid % 16) * 8;
  const int tn0 = (tid / 16) * 8;
  float acc[8][8];
#pragma unroll
  for (int i = 0; i < 8; ++i)
#pragma unroll
    for (int j = 0; j < 8; ++j) acc[i][j] = 0.0f;

  for (int k0 = 0; k0 < K; k0 += BK) {
#pragma unroll
    for (int l = 0; l < 2; ++l) {  // A tile: 128x16 = 512 float4
      int idx = tid + l * 256;
      int row = idx >> 2;
      int kc = (idx & 3) << 2;
      int gm = bm + row, gk = k0 + kc;
      float4 av = make_float4(0.f, 0.f, 0.f, 0.f);
      if (gm < M) {
        float4 xv = *(const float4*)&X[(size_t)gm * K + gk];
        float4 sv = *(const float4*)&s[gk];
        float4 tv = *(const float4*)&t[gk];
        av.x = fmaf(xv.x, sv.x, tv.x);
        av.y = fmaf(xv.y, sv.y, tv.y);
        av.z = fmaf(xv.z, sv.z, tv.z);
        av.w = fmaf(xv.w, sv.w, tv.w);
      }
      As[kc + 0][row] = av.x;
      As[kc + 1][row] = av.y;
      As[kc + 2][row] = av.z;
      As[kc + 3][row] = av.w;
    }
#pragma unroll
    for (int l = 0; l < 2; ++l) {  // B tile: 16x128 = 512 float4
      int idx = tid + l * 256;
      int row = idx >> 5;
      int c = (idx & 31) << 2;
      *(float4*)&Bs[row][c] = *(const float4*)&W[(size_t)(k0 + row) * N + bn + c];
    }
    __syncthreads();
#pragma unroll
    for (int k = 0; k < BK; ++k) {
      float a[8], b[8];
      *(float4*)&a[0] = *(const float4*)&As[k][tm0];
      *(float4*)&a[4] = *(const float4*)&As[k][tm0 + 4];
      *(float4*)&b[0] = *(const float4*)&Bs[k][tn0];
      *(float4*)&b[4] = *(const float4*)&Bs[k][tn0 + 4];
#pragma unroll
      for (int i = 0; i < 8; ++i)
#pragma unroll
        for (int j = 0; j < 8; ++j) acc[i][j] = fmaf(a[i], b[j], acc[i][j]);
    }
    __syncthreads();
  }
  const int halfN = N >> 1;
#pragma unroll
  for (int i = 0; i < 8; ++i) {
    int gm = bm + tm0 + i;
    if (gm < M) {
      float di = dinv[gm];
      uint4 o;
      o.x = pack_bf2(acc[i][0] * di, acc[i][1] * di);
      o.y = pack_bf2(acc[i][2] * di, acc[i][3] * di);
      o.z = pack_bf2(acc[i][4] * di, acc[i][5] * di);
      o.w = pack_bf2(acc[i][6] * di, acc[i][7] * di);
      *(uint4*)&outbf[(size_t)gm * halfN + ((bn + tn0) >> 1)] = o;
    }
  }
}

// ---------------- pull aggregation + bias + ReLU ----------------
// Hs = bf16x2 rows, pre-scaled by dinv[src].
// out[d] = relu( dinv[d] * ( sum_e Hs[src_e] + Hs[d] ) + bias )
template <int F>
__global__ __launch_bounds__(256) void agg_kernel(const unsigned int* __restrict__ Hs,
                                                  const int* __restrict__ row_ptr,
                                                  const int* __restrict__ csr_src,
                                                  const float* __restrict__ dinv,
                                                  const float* __restrict__ bias,
                                                  float* __restrict__ out, int n) {
  constexpr int LPN = F / 2;           // lanes per node (each lane = 2 features)
  constexpr int NODES = 256 / LPN;
  int node = blockIdx.x * NODES + threadIdx.x / LPN;
  int f2 = threadIdx.x % LPN;
  if (node >= n) return;
  unsigned int su = Hs[(size_t)node * LPN + f2];   // self term (already dinv[d]-scaled)
  float a0 = bf_lo(su), a1 = bf_hi(su);
  float b0 = 0.f, b1 = 0.f, c0 = 0.f, c1 = 0.f, d0 = 0.f, d1 = 0.f;
  int e = row_ptr[node];
  const int e1 = row_ptr[node + 1];
  for (; e + 4 <= e1; e += 4) {
    int s0 = csr_src[e], s1 = csr_src[e + 1], s2 = csr_src[e + 2], s3 = csr_src[e + 3];
    unsigned int u0 = Hs[(size_t)s0 * LPN + f2];
    unsigned int u1 = Hs[(size_t)s1 * LPN + f2];
    unsigned int u2 = Hs[(size_t)s2 * LPN + f2];
    unsigned int u3 = Hs[(size_t)s3 * LPN + f2];
    a0 += bf_lo(u0); a1 += bf_hi(u0);
    b0 += bf_lo(u1); b1 += bf_hi(u1);
    c0 += bf_lo(u2); c1 += bf_hi(u2);
    d0 += bf_lo(u3); d1 += bf_hi(u3);
  }
  for (; e < e1; ++e) {
    int s0 = csr_src[e];
    unsigned int u0 = Hs[(size_t)s0 * LPN + f2];
    a0 += bf_lo(u0); a1 += bf_hi(u0);
  }
  float di = dinv[node];
  float2 bv = *(const float2*)&bias[2 * f2];
  float r0 = fmaf(di, (a0 + b0) + (c0 + d0), bv.x);
  float r1 = fmaf(di, (a1 + b1) + (c1 + d1), bv.y);
  float2 o = make_float2(fmaxf(r0, 0.f), fmaxf(r1, 0.f));
  *(float2*)&out[(size_t)node * F + 2 * f2] = o;
}

// ---------------- final LN + mean pool (collapsed) ----------------
__global__ __launch_bounds__(128) void colsum_kernel(const float* __restrict__ c2, int n,
                                                     double* __restrict__ colpart,
                                                     double* __restrict__ qpart) {
  int c = threadIdx.x;
  int b = blockIdx.x, B = gridDim.x;
  int rows_per = (n + B - 1) / B;
  int r0 = b * rows_per, r1 = min(n, r0 + rows_per);
  double s = 0.0, q = 0.0;
  for (int r = r0; r < r1; ++r) {
    float v = c2[(size_t)r * OUT_F + c];
    s += v;
    q += (double)v * v;
  }
  colpart[(size_t)b * OUT_F + c] = s;
  __shared__ double sh[128];
  sh[c] = q;
  __syncthreads();
  for (int off = 64; off > 0; off >>= 1) {
    if (c < off) sh[c] += sh[c + off];
    __syncthreads();
  }
  if (c == 0) qpart[b] = sh[0];
}

__global__ __launch_bounds__(128) void final_kernel(const double* __restrict__ colpart,
                                                    const double* __restrict__ qpart, int B, int n,
                                                    const float* __restrict__ lnw,
                                                    const float* __restrict__ lnb,
                                                    float* __restrict__ out) {
  int c = threadIdx.x;
  double s = 0.0;
  for (int b = 0; b < B; ++b) s += colpart[(size_t)b * OUT_F + c];
  double q = 0.0;
  for (int b = c; b < B; b += 128) q += qpart[b];
  __shared__ double shq[128], shs[128];
  shq[c] = q; shs[c] = s;
  __syncthreads();
  for (int off = 64; off > 0; off >>= 1) {
    if (c < off) { shq[c] += shq[c + off]; shs[c] += shs[c + off]; }
    __syncthreads();
  }
  double cnt = (double)n * (double)OUT_F;
  double mean = shs[0] / cnt;
  double var = shq[0] / cnt - mean * mean;
  double inv = 1.0 / sqrt(var + 1e-5);
  double colmean = s / (double)n;
  out[c] = (float)((colmean - mean) * inv * (double)lnw[c] + (double)lnb[c]);
}

// ---------------- launch ----------------
extern "C" void kernel_launch(void* const* d_in, const int* in_sizes, int n_in,
                              void* d_out, int out_size, void* d_ws, size_t ws_size,
                              hipStream_t stream) {
  const float* x   = (const float*)d_in[0];
  const int*  ei   = (const int*)d_in[1];
  const float* W1  = (const float*)d_in[2];
  const float* b1  = (const float*)d_in[3];
  const float* W2  = (const float*)d_in[4];
  const float* b2  = (const float*)d_in[5];
  const float* ln0w = (const float*)d_in[6];
  const float* ln0b = (const float*)d_in[7];
  const float* ln1w = (const float*)d_in[8];
  const float* ln1b = (const float*)d_in[9];
  const float* ln2w = (const float*)d_in[10];
  const float* ln2b = (const float*)d_in[11];

  const int N = in_sizes[0] / IN_F;
  const int E = in_sizes[1] / 2;
  const int* src = ei;
  const int* dst = ei + E;

  char* ws = (char*)d_ws;
  size_t off = 0;
  auto alloc = [&](size_t bytes) -> void* {
    void* p = ws + off;
    off += (bytes + 255) & ~(size_t)255;
    return p;
  };
  int*    counts  = (int*)alloc((size_t)N * 4);        // zeroed
  int*    fill    = (int*)alloc((size_t)N * 4);        // zeroed
  size_t zero_bytes = off;
  float*  dinv    = (float*)alloc((size_t)N * 4);
  int*    row_ptr = (int*)alloc((size_t)(N + 1) * 4);
  int*    csr_src = (int*)alloc((size_t)E * 4);
  double* psum    = (double*)alloc(G_STATS * 8);
  double* psq     = (double*)alloc(G_STATS * 8);
  double* colpart = (double*)alloc((size_t)B_COL * OUT_F * 8);
  double* qpart   = (double*)alloc((size_t)B_COL * 8);
  float*  s0      = (float*)alloc(IN_F * 4);
  float*  t0      = (float*)alloc(IN_F * 4);
  float*  s1      = (float*)alloc(HID_F * 4);
  float*  t1      = (float*)alloc(HID_F * 4);
  // h buffers hold bf16x2-packed, dinv-scaled GEMM outputs
  unsigned int* h1 = (unsigned int*)alloc((size_t)N * (HID_F / 2) * 4);  // 25.6 MB
  float*  c1      = (float*)alloc((size_t)N * HID_F * 4);                // 51.2 MB
  unsigned int* h2 = h1;                       // reuse: h1 dead after agg1
  float*  c2 = c1;                             // reuse: c1 dead after gemm2

  hipMemsetAsync(ws, 0, zero_bytes, stream);

  // graph prep
  count_kernel<<<1024, 256, 0, stream>>>(dst, E, counts);
  dinv_kernel<<<(N + 255) / 256, 256, 0, stream>>>(counts, dinv, N);
  scan_kernel<<<1, 1024, 0, stream>>>(counts, row_ptr, N);
  scatter_kernel<<<1024, 256, 0, stream>>>(src, dst, E, row_ptr, fill, csr_src);

  // LN0 stats (over x) -> fused scale/shift
  stats_partial<<<G_STATS, 256, 0, stream>>>((const float4*)x, (long)N * IN_F / 4, psum, psq);
  finalize_ln<<<1, 512, 0, stream>>>(psum, psq, G_STATS, 1.0 / ((double)N * IN_F), ln0w, ln0b, s0, t0, IN_F);

  // conv1: h1 = bf16(dinv * (LN0(x) @ W1)) ; agg -> c1 (bias+relu fused)
  dim3 g1((N + BM - 1) / BM, HID_F / BN);
  gemm_ln<<<g1, 256, 0, stream>>>(x, N, IN_F, HID_F, W1, s0, t0, dinv, h1);
  agg_kernel<HID_F><<<(N + 1) / 2, 256, 0, stream>>>(h1, row_ptr, csr_src, dinv, b1, c1, N);

  // LN1 stats (over c1)
  stats_partial<<<G_STATS, 256, 0, stream>>>((const float4*)c1, (long)N * HID_F / 4, psum, psq);
  finalize_ln<<<1, 256, 0, stream>>>(psum, psq, G_STATS, 1.0 / ((double)N * HID_F), ln1w, ln1b, s1, t1, HID_F);

  // conv2: h2 = bf16(dinv * (LN1(c1) @ W2)) ; agg -> c2
  dim3 g2((N + BM - 1) / BM, OUT_F / BN);
  gemm_ln<<<g2, 256, 0, stream>>>(c1, N, HID_F, OUT_F, W2, s1, t1, dinv, h2);
  agg_kernel<OUT_F><<<(N + 3) / 4, 256, 0, stream>>>(h2, row_ptr, csr_src, dinv, b2, c2, N);

  // final LN + mean pool
  colsum_kernel<<<B_COL, 128, 0, stream>>>(c2, N, colpart, qpart);
  final_kernel<<<1, 128, 0, stream>>>(colpart, qpart, B_COL, N, ln2w, ln2b, (float*)d_out);
}

// Round 6
// 820.911 us; speedup vs baseline: 1.5790x; 1.2304x over previous
//
#include <hip/hip_runtime.h>

typedef unsigned short u16;
typedef __attribute__((ext_vector_type(8))) short bf16x8;
typedef __attribute__((ext_vector_type(4))) float f32x4;

// Problem constants
#define IN_F  512
#define HID_F 256
#define OUT_F 128
#define G_STATS 1024   // blocks for input stats partial reduction
#define B_COL   512    // blocks for column-sum reduction

// ---------------- helpers ----------------
__device__ inline u16 f2bf_rne(float f) {
  unsigned int u = __float_as_uint(f);
  unsigned int r = (u + 0x7fffu + ((u >> 16) & 1u)) >> 16;
  return (u16)r;
}
__device__ inline unsigned int pack_bf2(float lo, float hi) {
  return (unsigned int)f2bf_rne(lo) | ((unsigned int)f2bf_rne(hi) << 16);
}
__device__ inline float bf_lo(unsigned int u) { return __uint_as_float(u << 16); }
__device__ inline float bf_hi(unsigned int u) { return __uint_as_float(u & 0xffff0000u); }

// ---------------- graph prep ----------------
__global__ __launch_bounds__(256) void count_kernel(const int* __restrict__ dst, int E,
                                                    int* __restrict__ counts) {
  int stride = gridDim.x * blockDim.x;
  for (int i = blockIdx.x * blockDim.x + threadIdx.x; i < E; i += stride)
    atomicAdd(&counts[dst[i]], 1);
}

__global__ __launch_bounds__(256) void dinv_kernel(const int* __restrict__ counts,
                                                   float* __restrict__ dinv, int n) {
  int i = blockIdx.x * blockDim.x + threadIdx.x;
  if (i < n) dinv[i] = rsqrtf((float)counts[i] + 1.0f);  // +1 self-loop, always > 0
}

// Exclusive scan of counts[n] -> row_ptr[n+1], single block of 1024 threads.
__global__ __launch_bounds__(1024) void scan_kernel(const int* __restrict__ counts,
                                                    int* __restrict__ row_ptr, int n) {
  __shared__ int wsum[16];
  __shared__ int s_carry, s_total;
  const int tid = threadIdx.x;
  const int lane = tid & 63, wid = tid >> 6;
  if (tid == 0) { s_carry = 0; row_ptr[0] = 0; }
  __syncthreads();
  const int PER = 8, CH = 1024 * PER;
  for (int base = 0; base < n; base += CH) {
    int i0 = base + tid * PER;
    int v[PER];
    int s = 0;
#pragma unroll
    for (int j = 0; j < PER; ++j) { int i = i0 + j; int c = (i < n) ? counts[i] : 0; s += c; v[j] = s; }
    int ts = s;
#pragma unroll
    for (int off = 1; off < 64; off <<= 1) {
      int o = __shfl_up(ts, off, 64);
      if (lane >= off) ts += o;
    }
    if (lane == 63) wsum[wid] = ts;
    __syncthreads();
    if (tid == 0) {
      int c = 0;
#pragma unroll
      for (int w = 0; w < 16; ++w) { int t = wsum[w]; wsum[w] = c; c += t; }
      s_total = c;
    }
    __syncthreads();
    int base_excl = s_carry + wsum[wid] + (ts - s);
#pragma unroll
    for (int j = 0; j < PER; ++j) { int i = i0 + j; if (i < n) row_ptr[i + 1] = base_excl + v[j]; }
    __syncthreads();
    if (tid == 0) s_carry += s_total;
    __syncthreads();
  }
}

__global__ __launch_bounds__(256) void scatter_kernel(const int* __restrict__ src,
                                                      const int* __restrict__ dst, int E,
                                                      const int* __restrict__ row_ptr,
                                                      int* __restrict__ fill,
                                                      int* __restrict__ csr_src) {
  int stride = gridDim.x * blockDim.x;
  for (int i = blockIdx.x * blockDim.x + threadIdx.x; i < E; i += stride) {
    int d = dst[i];
    int p = row_ptr[d] + atomicAdd(&fill[d], 1);
    csr_src[p] = src[i];
  }
}

// ---------------- LN stats over x ----------------
__global__ __launch_bounds__(256) void stats_partial(const float4* __restrict__ x, long n4,
                                                     double* __restrict__ psum,
                                                     double* __restrict__ psq) {
  double s = 0.0, q = 0.0;
  long stride = (long)gridDim.x * 256;
  for (long i = (long)blockIdx.x * 256 + threadIdx.x; i < n4; i += stride) {
    float4 v = x[i];
    s += (double)((v.x + v.y) + (v.z + v.w));
    q += (double)v.x * v.x + (double)v.y * v.y + (double)v.z * v.z + (double)v.w * v.w;
  }
  __shared__ double sh[256], sh2[256];
  sh[threadIdx.x] = s; sh2[threadIdx.x] = q;
  __syncthreads();
  for (int off = 128; off > 0; off >>= 1) {
    if (threadIdx.x < off) { sh[threadIdx.x] += sh[threadIdx.x + off]; sh2[threadIdx.x] += sh2[threadIdx.x + off]; }
    __syncthreads();
  }
  if (threadIdx.x == 0) { psum[blockIdx.x] = sh[0]; psq[blockIdx.x] = sh2[0]; }
}

// Reduce partials, then write per-channel fused scale/shift: a = x*s[k] + t[k]
__global__ __launch_bounds__(512) void finalize_ln(const double* __restrict__ psum,
                            const double* __restrict__ psq,
                            int nb, double inv_count,
                            const float* __restrict__ lnw, const float* __restrict__ lnb,
                            float* __restrict__ s, float* __restrict__ t, int C) {
  double a = 0.0, b = 0.0;
  for (int i = threadIdx.x; i < nb; i += blockDim.x) { a += psum[i]; b += psq[i]; }
  __shared__ double sa[512], sb[512];
  sa[threadIdx.x] = a; sb[threadIdx.x] = b;
  __syncthreads();
  for (int off = blockDim.x >> 1; off > 0; off >>= 1) {
    if ((int)threadIdx.x < off) { sa[threadIdx.x] += sa[threadIdx.x + off]; sb[threadIdx.x] += sb[threadIdx.x + off]; }
    __syncthreads();
  }
  double mean = sa[0] * inv_count;
  double var  = sb[0] * inv_count - mean * mean;
  double inv  = 1.0 / sqrt(var + 1e-5);
  int k = threadIdx.x;
  if (k < C) {
    double sc = inv * (double)lnw[k];
    s[k] = (float)sc;
    t[k] = (float)((double)lnb[k] - mean * sc);
  }
}

// ---------------- activation prep: LN-fused fp32 -> bf16 ----------------
// out[idx] = bf16( in[idx]*s[k] + t[k] ),  k = idx & kmask  (K power of 2)
__global__ __launch_bounds__(256) void a_prep(const float* __restrict__ in,
                                              const float* __restrict__ s,
                                              const float* __restrict__ t,
                                              u16* __restrict__ out, long total8, int kmask) {
  long stride = (long)gridDim.x * 256;
  for (long i = (long)blockIdx.x * 256 + threadIdx.x; i < total8; i += stride) {
    long idx = i * 8;
    int k = (int)(idx & kmask);
    float4 v0 = *(const float4*)&in[idx];
    float4 v1 = *(const float4*)&in[idx + 4];
    float4 sA = *(const float4*)&s[k];
    float4 sB = *(const float4*)&s[k + 4];
    float4 tA = *(const float4*)&t[k];
    float4 tB = *(const float4*)&t[k + 4];
    float a0 = fmaf(v0.x, sA.x, tA.x), a1 = fmaf(v0.y, sA.y, tA.y);
    float a2 = fmaf(v0.z, sA.z, tA.z), a3 = fmaf(v0.w, sA.w, tA.w);
    float a4 = fmaf(v1.x, sB.x, tB.x), a5 = fmaf(v1.y, sB.y, tB.y);
    float a6 = fmaf(v1.z, sB.z, tB.z), a7 = fmaf(v1.w, sB.w, tB.w);
    uint4 o;
    o.x = pack_bf2(a0, a1); o.y = pack_bf2(a2, a3);
    o.z = pack_bf2(a4, a5); o.w = pack_bf2(a6, a7);
    *(uint4*)&out[idx] = o;
  }
}

// ---------------- weight transpose+convert: W[K][N] f32 -> Wt[N][K] bf16 ----------------
__global__ __launch_bounds__(256) void wt_kernel(const float* __restrict__ W,
                                                 u16* __restrict__ Wt, int K, int N) {
  __shared__ float tile[32][33];
  int n0 = blockIdx.x * 32, k0 = blockIdx.y * 32;
  int tx = threadIdx.x & 31, ty = threadIdx.x >> 5;  // ty 0..7
  for (int r = ty; r < 32; r += 8) tile[r][tx] = W[(size_t)(k0 + r) * N + n0 + tx];
  __syncthreads();
  for (int r = ty; r < 32; r += 8) Wt[(size_t)(n0 + r) * K + k0 + tx] = f2bf_rne(tile[tx][r]);
}

// ---------------- MFMA bf16 GEMM: H = bf16(dinv[m] * (A @ Wt^T)) ----------------
// A [Mpad][K] bf16 row-major, Wt [N][K] bf16 row-major (i.e. W^T).
// 128x128 tile, BK=64, 4 waves (2x2), each wave 64x64 = 4x4 16x16x32 fragments.
// LDS XOR-swizzle: 16B slot ^= (row&7) on both ds_write and ds_read (2-way, free).
__global__ __launch_bounds__(256) void gemm_mfma(const u16* __restrict__ A,
                                                 const u16* __restrict__ Bt,
                                                 int M, int K, int N,
                                                 const float* __restrict__ dinv,
                                                 u16* __restrict__ H) {
  __shared__ u16 As[128 * 64];
  __shared__ u16 Bs[128 * 64];
  const int tid = threadIdx.x;
  const int lane = tid & 63;
  const int wid = tid >> 6;
  const int wr = wid >> 1, wc = wid & 1;
  const int bm = blockIdx.x * 128;
  const int bn = blockIdx.y * 128;

  f32x4 acc[4][4] = {};

  for (int k0 = 0; k0 < K; k0 += 64) {
#pragma unroll
    for (int i = 0; i < 4; ++i) {
      int idx = i * 256 + tid;          // 0..1023
      int row = idx >> 3;               // 0..127
      int slot = idx & 7;
      int wsi = row * 64 + ((slot ^ (row & 7)) * 8);
      uint4 va = *(const uint4*)&A[(size_t)(bm + row) * K + k0 + slot * 8];
      *(uint4*)&As[wsi] = va;
      uint4 vb = *(const uint4*)&Bt[(size_t)(bn + row) * K + k0 + slot * 8];
      *(uint4*)&Bs[wsi] = vb;
    }
    __syncthreads();
#pragma unroll
    for (int ko = 0; ko < 2; ++ko) {
      bf16x8 af[4], bfr[4];
#pragma unroll
      for (int i = 0; i < 4; ++i) {
        int ar = wr * 64 + i * 16 + (lane & 15);
        int as = (ko * 4 + (lane >> 4)) ^ (ar & 7);
        af[i] = *(const bf16x8*)&As[ar * 64 + as * 8];
        int br = wc * 64 + i * 16 + (lane & 15);
        int bs = (ko * 4 + (lane >> 4)) ^ (br & 7);
        bfr[i] = *(const bf16x8*)&Bs[br * 64 + bs * 8];
      }
#pragma unroll
      for (int mi = 0; mi < 4; ++mi)
#pragma unroll
        for (int ni = 0; ni < 4; ++ni)
          acc[mi][ni] = __builtin_amdgcn_mfma_f32_16x16x32_bf16(af[mi], bfr[ni], acc[mi][ni], 0, 0, 0);
    }
    __syncthreads();
  }

  // epilogue: C/D layout col = lane&15, row = (lane>>4)*4 + j  [m89-verified]
  const int rg = (lane >> 4) * 4;
  const int cn = lane & 15;
#pragma unroll
  for (int mi = 0; mi < 4; ++mi) {
#pragma unroll
    for (int j = 0; j < 4; ++j) {
      int m = bm + wr * 64 + mi * 16 + rg + j;
      if (m < M) {
        float di = dinv[m];
#pragma unroll
        for (int ni = 0; ni < 4; ++ni) {
          int n = bn + wc * 64 + ni * 16 + cn;
          H[(size_t)m * N + n] = f2bf_rne(acc[mi][ni][j] * di);
        }
      }
    }
  }
}

// ---------------- pull aggregation + bias + ReLU (+optional fused LN stats) ----------------
// Hs = bf16x2 rows, pre-scaled by dinv[src].
// out[d] = relu( dinv[d] * ( sum_e Hs[src_e] + Hs[d] ) + bias )
template <int F, bool STATS>
__global__ __launch_bounds__(256) void agg_kernel(const unsigned int* __restrict__ Hs,
                                                  const int* __restrict__ row_ptr,
                                                  const int* __restrict__ csr_src,
                                                  const float* __restrict__ dinv,
                                                  const float* __restrict__ bias,
                                                  float* __restrict__ out, int n,
                                                  double* __restrict__ psum,
                                                  double* __restrict__ psq) {
  constexpr int LPN = F / 2;           // lanes per node (each lane = 2 features)
  constexpr int NODES = 256 / LPN;
  int node = blockIdx.x * NODES + threadIdx.x / LPN;
  int f2 = threadIdx.x % LPN;
  float r0 = 0.f, r1 = 0.f;
  if (node < n) {
    unsigned int su = Hs[(size_t)node * LPN + f2];   // self term (already dinv[d]-scaled)
    float a0 = bf_lo(su), a1 = bf_hi(su);
    float b0 = 0.f, b1 = 0.f, c0 = 0.f, c1 = 0.f, d0 = 0.f, d1 = 0.f;
    int e = row_ptr[node];
    const int e1 = row_ptr[node + 1];
    for (; e + 4 <= e1; e += 4) {
      int s0 = csr_src[e], s1 = csr_src[e + 1], s2 = csr_src[e + 2], s3 = csr_src[e + 3];
      unsigned int u0 = Hs[(size_t)s0 * LPN + f2];
      unsigned int u1 = Hs[(size_t)s1 * LPN + f2];
      unsigned int u2 = Hs[(size_t)s2 * LPN + f2];
      unsigned int u3 = Hs[(size_t)s3 * LPN + f2];
      a0 += bf_lo(u0); a1 += bf_hi(u0);
      b0 += bf_lo(u1); b1 += bf_hi(u1);
      c0 += bf_lo(u2); c1 += bf_hi(u2);
      d0 += bf_lo(u3); d1 += bf_hi(u3);
    }
    for (; e < e1; ++e) {
      int s0 = csr_src[e];
      unsigned int u0 = Hs[(size_t)s0 * LPN + f2];
      a0 += bf_lo(u0); a1 += bf_hi(u0);
    }
    float di = dinv[node];
    float2 bv = *(const float2*)&bias[2 * f2];
    r0 = fmaxf(fmaf(di, (a0 + b0) + (c0 + d0), bv.x), 0.f);
    r1 = fmaxf(fmaf(di, (a1 + b1) + (c1 + d1), bv.y), 0.f);
    float2 o = make_float2(r0, r1);
    *(float2*)&out[(size_t)node * F + 2 * f2] = o;
  }
  if constexpr (STATS) {
    __shared__ double sh[256], sh2[256];
    sh[threadIdx.x] = (double)r0 + (double)r1;
    sh2[threadIdx.x] = (double)r0 * r0 + (double)r1 * r1;
    __syncthreads();
    for (int off = 128; off > 0; off >>= 1) {
      if ((int)threadIdx.x < off) { sh[threadIdx.x] += sh[threadIdx.x + off]; sh2[threadIdx.x] += sh2[threadIdx.x + off]; }
      __syncthreads();
    }
    if (threadIdx.x == 0) { psum[blockIdx.x] = sh[0]; psq[blockIdx.x] = sh2[0]; }
  }
}

// ---------------- final LN + mean pool (collapsed) ----------------
__global__ __launch_bounds__(128) void colsum_kernel(const float* __restrict__ c2, int n,
                                                     double* __restrict__ colpart,
                                                     double* __restrict__ qpart) {
  int c = threadIdx.x;
  int b = blockIdx.x, B = gridDim.x;
  int rows_per = (n + B - 1) / B;
  int r0 = b * rows_per, r1 = min(n, r0 + rows_per);
  double s = 0.0, q = 0.0;
  for (int r = r0; r < r1; ++r) {
    float v = c2[(size_t)r * OUT_F + c];
    s += v;
    q += (double)v * v;
  }
  colpart[(size_t)b * OUT_F + c] = s;
  __shared__ double sh[128];
  sh[c] = q;
  __syncthreads();
  for (int off = 64; off > 0; off >>= 1) {
    if (c < off) sh[c] += sh[c + off];
    __syncthreads();
  }
  if (c == 0) qpart[b] = sh[0];
}

__global__ __launch_bounds__(128) void final_kernel(const double* __restrict__ colpart,
                                                    const double* __restrict__ qpart, int B, int n,
                                                    const float* __restrict__ lnw,
                                                    const float* __restrict__ lnb,
                                                    float* __restrict__ out) {
  int c = threadIdx.x;
  double s = 0.0;
  for (int b = 0; b < B; ++b) s += colpart[(size_t)b * OUT_F + c];
  double q = 0.0;
  for (int b = c; b < B; b += 128) q += qpart[b];
  __shared__ double shq[128], shs[128];
  shq[c] = q; shs[c] = s;
  __syncthreads();
  for (int off = 64; off > 0; off >>= 1) {
    if (c < off) { shq[c] += shq[c + off]; shs[c] += shs[c + off]; }
    __syncthreads();
  }
  double cnt = (double)n * (double)OUT_F;
  double mean = shs[0] / cnt;
  double var = shq[0] / cnt - mean * mean;
  double inv = 1.0 / sqrt(var + 1e-5);
  double colmean = s / (double)n;
  out[c] = (float)((colmean - mean) * inv * (double)lnw[c] + (double)lnb[c]);
}

// ---------------- launch ----------------
extern "C" void kernel_launch(void* const* d_in, const int* in_sizes, int n_in,
                              void* d_out, int out_size, void* d_ws, size_t ws_size,
                              hipStream_t stream) {
  const float* x   = (const float*)d_in[0];
  const int*  ei   = (const int*)d_in[1];
  const float* W1  = (const float*)d_in[2];
  const float* b1  = (const float*)d_in[3];
  const float* W2  = (const float*)d_in[4];
  const float* b2  = (const float*)d_in[5];
  const float* ln0w = (const float*)d_in[6];
  const float* ln0b = (const float*)d_in[7];
  const float* ln1w = (const float*)d_in[8];
  const float* ln1b = (const float*)d_in[9];
  const float* ln2w = (const float*)d_in[10];
  const float* ln2b = (const float*)d_in[11];

  const int N = in_sizes[0] / IN_F;
  const int E = in_sizes[1] / 2;
  const int Mpad = ((N + 127) / 128) * 128;
  const int* src = ei;
  const int* dst = ei + E;

  const int agg1_blocks = (N + 1) / 2;    // 2 nodes/block at F=256
  const int agg2_blocks = (N + 3) / 4;    // 4 nodes/block at F=128

  char* ws = (char*)d_ws;
  size_t off = 0;
  auto alloc = [&](size_t bytes) -> void* {
    void* p = ws + off;
    off += (bytes + 255) & ~(size_t)255;
    return p;
  };
  int*    counts  = (int*)alloc((size_t)N * 4);        // zeroed
  int*    fill    = (int*)alloc((size_t)N * 4);        // zeroed
  size_t zero_bytes = off;
  float*  dinv    = (float*)alloc((size_t)N * 4);
  int*    row_ptr = (int*)alloc((size_t)(N + 1) * 4);
  int*    csr_src = (int*)alloc((size_t)E * 4);
  int     nb_max  = agg1_blocks > G_STATS ? agg1_blocks : G_STATS;
  double* psum    = (double*)alloc((size_t)nb_max * 8);
  double* psq     = (double*)alloc((size_t)nb_max * 8);
  double* colpart = (double*)alloc((size_t)B_COL * OUT_F * 8);
  double* qpart   = (double*)alloc((size_t)B_COL * 8);
  float*  s0      = (float*)alloc(IN_F * 4);
  float*  t0      = (float*)alloc(IN_F * 4);
  float*  s1      = (float*)alloc(HID_F * 4);
  float*  t1      = (float*)alloc(HID_F * 4);
  u16*    Wt1     = (u16*)alloc((size_t)HID_F * IN_F * 2);
  u16*    Wt2     = (u16*)alloc((size_t)OUT_F * HID_F * 2);
  u16*    a1      = (u16*)alloc((size_t)Mpad * IN_F * 2);   // 51.2 MB; reused for a2
  u16*    h1      = (u16*)alloc((size_t)N * HID_F * 2);     // 25.6 MB; reused for h2
  float*  c1      = (float*)alloc((size_t)N * HID_F * 4);   // 51.2 MB; reused for c2
  u16*    a2 = a1;     // a1 dead after gemm1
  u16*    h2 = h1;     // h1 dead after agg1
  float*  c2 = c1;     // c1 dead after a_prep #2

  hipMemsetAsync(ws, 0, zero_bytes, stream);

  // graph prep
  count_kernel<<<1024, 256, 0, stream>>>(dst, E, counts);
  dinv_kernel<<<(N + 255) / 256, 256, 0, stream>>>(counts, dinv, N);
  scan_kernel<<<1, 1024, 0, stream>>>(counts, row_ptr, N);
  scatter_kernel<<<1024, 256, 0, stream>>>(src, dst, E, row_ptr, fill, csr_src);

  // weight transposes (bf16)
  wt_kernel<<<dim3(HID_F / 32, IN_F / 32), 256, 0, stream>>>(W1, Wt1, IN_F, HID_F);
  wt_kernel<<<dim3(OUT_F / 32, HID_F / 32), 256, 0, stream>>>(W2, Wt2, HID_F, OUT_F);

  // LN0 stats (over x) -> fused scale/shift -> bf16 activation prep
  stats_partial<<<G_STATS, 256, 0, stream>>>((const float4*)x, (long)N * IN_F / 4, psum, psq);
  finalize_ln<<<1, 512, 0, stream>>>(psum, psq, G_STATS, 1.0 / ((double)N * IN_F), ln0w, ln0b, s0, t0, IN_F);
  a_prep<<<2048, 256, 0, stream>>>(x, s0, t0, a1, (long)N * IN_F / 8, IN_F - 1);

  // conv1: h1 = bf16(dinv * (a1 @ W1)) ; agg -> c1 (bias+relu+LN1 stats fused)
  gemm_mfma<<<dim3(Mpad / 128, HID_F / 128), 256, 0, stream>>>(a1, Wt1, N, IN_F, HID_F, dinv, h1);
  agg_kernel<HID_F, true><<<agg1_blocks, 256, 0, stream>>>((const unsigned int*)h1, row_ptr, csr_src,
                                                           dinv, b1, c1, N, psum, psq);
  finalize_ln<<<1, 512, 0, stream>>>(psum, psq, agg1_blocks, 1.0 / ((double)N * HID_F), ln1w, ln1b, s1, t1, HID_F);
  a_prep<<<2048, 256, 0, stream>>>(c1, s1, t1, a2, (long)N * HID_F / 8, HID_F - 1);

  // conv2: h2 = bf16(dinv * (a2 @ W2)) ; agg -> c2
  gemm_mfma<<<dim3(Mpad / 128, OUT_F / 128), 256, 0, stream>>>(a2, Wt2, N, HID_F, OUT_F, dinv, h2);
  agg_kernel<OUT_F, false><<<agg2_blocks, 256, 0, stream>>>((const unsigned int*)h2, row_ptr, csr_src,
                                                            dinv, b2, c2, N, nullptr, nullptr);

  // final LN + mean pool
  colsum_kernel<<<B_COL, 128, 0, stream>>>(c2, N, colpart, qpart);
  final_kernel<<<1, 128, 0, stream>>>(colpart, qpart, B_COL, N, ln2w, ln2b, (float*)d_out);
}

// Round 9
// 701.521 us; speedup vs baseline: 1.8478x; 1.1702x over previous
//
#include <hip/hip_runtime.h>

typedef unsigned short u16;
typedef __attribute__((ext_vector_type(8))) short bf16x8;
typedef __attribute__((ext_vector_type(4))) float f32x4;

// Problem constants
#define IN_F  512
#define HID_F 256
#define OUT_F 128
#define G_STATS 1024   // blocks for input stats partial reduction

// ---------------- helpers ----------------
__device__ inline u16 f2bf_rne(float f) {
  unsigned int u = __float_as_uint(f);
  unsigned int r = (u + 0x7fffu + ((u >> 16) & 1u)) >> 16;
  return (u16)r;
}
__device__ inline unsigned int pack_bf2(float lo, float hi) {
  return (unsigned int)f2bf_rne(lo) | ((unsigned int)f2bf_rne(hi) << 16);
}
__device__ inline float bf_lo(unsigned int u) { return __uint_as_float(u << 16); }
__device__ inline float bf_hi(unsigned int u) { return __uint_as_float(u & 0xffff0000u); }

// ---------------- graph prep ----------------
__global__ __launch_bounds__(256) void count_kernel(const int* __restrict__ dst, int E,
                                                    int* __restrict__ counts) {
  int stride = gridDim.x * blockDim.x;
  for (int i = blockIdx.x * blockDim.x + threadIdx.x; i < E; i += stride)
    atomicAdd(&counts[dst[i]], 1);
}

__global__ __launch_bounds__(256) void dinv_kernel(const int* __restrict__ counts,
                                                   float* __restrict__ dinv, int n) {
  int i = blockIdx.x * blockDim.x + threadIdx.x;
  if (i < n) dinv[i] = rsqrtf((float)counts[i] + 1.0f);  // +1 self-loop, always > 0
}

// Exclusive scan of counts[n] -> row_ptr[n+1], single block of 1024 threads.
// Coalesced int4 loads + aligned int4 stores (row_ptr[i] = exclusive prefix).
__global__ __launch_bounds__(1024) void scan_kernel(const int* __restrict__ counts,
                                                    int* __restrict__ row_ptr, int n) {
  __shared__ int wsum[16];
  __shared__ int s_carry, s_total;
  const int tid = threadIdx.x;
  const int lane = tid & 63, wid = tid >> 6;
  if (tid == 0) s_carry = 0;
  __syncthreads();
  const int PER = 8, CH = 1024 * PER;
  for (int base = 0; base < n; base += CH) {
    int i0 = base + tid * PER;
    int v[PER];
    int s = 0;
    if (i0 + PER <= n) {
      int4 a = *(const int4*)&counts[i0];
      int4 b = *(const int4*)&counts[i0 + 4];
      int c[8] = {a.x, a.y, a.z, a.w, b.x, b.y, b.z, b.w};
#pragma unroll
      for (int j = 0; j < 8; ++j) { s += c[j]; v[j] = s; }
    } else {
#pragma unroll
      for (int j = 0; j < PER; ++j) { int i = i0 + j; int c = (i < n) ? counts[i] : 0; s += c; v[j] = s; }
    }
    int ts = s;
#pragma unroll
    for (int off = 1; off < 64; off <<= 1) {
      int o = __shfl_up(ts, off, 64);
      if (lane >= off) ts += o;
    }
    if (lane == 63) wsum[wid] = ts;
    __syncthreads();
    if (tid == 0) {
      int c = 0;
#pragma unroll
      for (int w = 0; w < 16; ++w) { int t = wsum[w]; wsum[w] = c; c += t; }
      s_total = c;
    }
    __syncthreads();
    int base_excl = s_carry + wsum[wid] + (ts - s);
    if (i0 + PER <= n) {
      int4 o0 = make_int4(base_excl, base_excl + v[0], base_excl + v[1], base_excl + v[2]);
      int4 o1 = make_int4(base_excl + v[3], base_excl + v[4], base_excl + v[5], base_excl + v[6]);
      *(int4*)&row_ptr[i0] = o0;
      *(int4*)&row_ptr[i0 + 4] = o1;
    } else {
      for (int j = 0; j < PER; ++j) { int i = i0 + j; if (i < n) row_ptr[i] = base_excl + (j ? v[j - 1] : 0); }
    }
    __syncthreads();
    if (tid == 0) s_carry += s_total;
    __syncthreads();
  }
  if (tid == 0) row_ptr[n] = s_carry;
}

__global__ __launch_bounds__(256) void scatter_kernel(const int* __restrict__ src,
                                                      const int* __restrict__ dst, int E,
                                                      const int* __restrict__ row_ptr,
                                                      int* __restrict__ fill,
                                                      int* __restrict__ csr_src) {
  int stride = gridDim.x * blockDim.x;
  for (int i = blockIdx.x * blockDim.x + threadIdx.x; i < E; i += stride) {
    int d = dst[i];
    int p = row_ptr[d] + atomicAdd(&fill[d], 1);
    csr_src[p] = src[i];
  }
}

// ---------------- LN stats over x ----------------
__global__ __launch_bounds__(256) void stats_partial(const float4* __restrict__ x, long n4,
                                                     double* __restrict__ psum,
                                                     double* __restrict__ psq) {
  double s = 0.0, q = 0.0;
  long stride = (long)gridDim.x * 256;
  for (long i = (long)blockIdx.x * 256 + threadIdx.x; i < n4; i += stride) {
    float4 v = x[i];
    s += (double)((v.x + v.y) + (v.z + v.w));
    q += (double)v.x * v.x + (double)v.y * v.y + (double)v.z * v.z + (double)v.w * v.w;
  }
  __shared__ double sh[256], sh2[256];
  sh[threadIdx.x] = s; sh2[threadIdx.x] = q;
  __syncthreads();
  for (int off = 128; off > 0; off >>= 1) {
    if (threadIdx.x < off) { sh[threadIdx.x] += sh[threadIdx.x + off]; sh2[threadIdx.x] += sh2[threadIdx.x + off]; }
    __syncthreads();
  }
  if (threadIdx.x == 0) { psum[blockIdx.x] = sh[0]; psq[blockIdx.x] = sh2[0]; }
}

// Reduce partials, then write per-channel fused scale/shift: a = x*s[k] + t[k]
__global__ __launch_bounds__(512) void finalize_ln(const double* __restrict__ psum,
                            const double* __restrict__ psq,
                            int nb, double inv_count,
                            const float* __restrict__ lnw, const float* __restrict__ lnb,
                            float* __restrict__ s, float* __restrict__ t, int C) {
  double a = 0.0, b = 0.0;
  for (int i = threadIdx.x; i < nb; i += blockDim.x) { a += psum[i]; b += psq[i]; }
  __shared__ double sa[512], sb[512];
  sa[threadIdx.x] = a; sb[threadIdx.x] = b;
  __syncthreads();
  for (int off = blockDim.x >> 1; off > 0; off >>= 1) {
    if ((int)threadIdx.x < off) { sa[threadIdx.x] += sa[threadIdx.x + off]; sb[threadIdx.x] += sb[threadIdx.x + off]; }
    __syncthreads();
  }
  double mean = sa[0] * inv_count;
  double var  = sb[0] * inv_count - mean * mean;
  double inv  = 1.0 / sqrt(var + 1e-5);
  int k = threadIdx.x;
  if (k < C) {
    double sc = inv * (double)lnw[k];
    s[k] = (float)sc;
    t[k] = (float)((double)lnb[k] - mean * sc);
  }
}

// ---------------- weight transpose+convert: W[K][N] f32 -> Wt[N][K] bf16 ----------------
__global__ __launch_bounds__(256) void wt_kernel(const float* __restrict__ W,
                                                 u16* __restrict__ Wt, int K, int N) {
  __shared__ float tile[32][33];
  int n0 = blockIdx.x * 32, k0 = blockIdx.y * 32;
  int tx = threadIdx.x & 31, ty = threadIdx.x >> 5;  // ty 0..7
  for (int r = ty; r < 32; r += 8) tile[r][tx] = W[(size_t)(k0 + r) * N + n0 + tx];
  __syncthreads();
  for (int r = ty; r < 32; r += 8) Wt[(size_t)(n0 + r) * K + k0 + tx] = f2bf_rne(tile[tx][r]);
}

// ---------------- MFMA bf16 GEMM with fused LN on A: H = bf16(dinv[m]*(LN(X) @ Wt^T)) ----
// X [M][K] fp32 row-major; LN fused as x*s[k]+t[k], converted bf16 during staging
// (bit-identical to the previous separate a_prep pass).
// Wt [N][K] bf16 row-major (i.e. W^T). 128x128 tile, BK=64, 4 waves (2x2),
// each wave 64x64 = 4x4 16x16x32 fragments.
// LDS XOR-swizzle: 16B slot ^= (row&7) on both ds_write and ds_read.
__global__ __launch_bounds__(256) void gemm_ln_mfma(const float* __restrict__ X,
                                                    const u16* __restrict__ Bt,
                                                    int M, int K, int N,
                                                    const float* __restrict__ s,
                                                    const float* __restrict__ t,
                                                    const float* __restrict__ dinv,
                                                    u16* __restrict__ H) {
  __shared__ u16 As[128 * 64];
  __shared__ u16 Bs[128 * 64];
  const int tid = threadIdx.x;
  const int lane = tid & 63;
  const int wid = tid >> 6;
  const int wr = wid >> 1, wc = wid & 1;
  const int bm = blockIdx.x * 128;
  const int bn = blockIdx.y * 128;

  f32x4 acc[4][4] = {};

  for (int k0 = 0; k0 < K; k0 += 64) {
#pragma unroll
    for (int i = 0; i < 4; ++i) {
      int g = i * 256 + tid;            // 0..1023
      int row = g >> 3;                 // 0..127
      int slot = g & 7;
      int gk = k0 + slot * 8;
      int wsi = row * 64 + ((slot ^ (row & 7)) * 8);
      // A: fp32 -> LN fma -> bf16 pack
      int gm = bm + row;
      uint4 o = make_uint4(0u, 0u, 0u, 0u);
      if (gm < M) {
        float4 v0 = *(const float4*)&X[(size_t)gm * K + gk];
        float4 v1 = *(const float4*)&X[(size_t)gm * K + gk + 4];
        float4 sA = *(const float4*)&s[gk];
        float4 sB = *(const float4*)&s[gk + 4];
        float4 tA = *(const float4*)&t[gk];
        float4 tB = *(const float4*)&t[gk + 4];
        o.x = pack_bf2(fmaf(v0.x, sA.x, tA.x), fmaf(v0.y, sA.y, tA.y));
        o.y = pack_bf2(fmaf(v0.z, sA.z, tA.z), fmaf(v0.w, sA.w, tA.w));
        o.z = pack_bf2(fmaf(v1.x, sB.x, tB.x), fmaf(v1.y, sB.y, tB.y));
        o.w = pack_bf2(fmaf(v1.z, sB.z, tB.z), fmaf(v1.w, sB.w, tB.w));
      }
      *(uint4*)&As[wsi] = o;
      // B: straight bf16 copy
      uint4 vb = *(const uint4*)&Bt[(size_t)(bn + row) * K + gk];
      *(uint4*)&Bs[wsi] = vb;
    }
    __syncthreads();
#pragma unroll
    for (int ko = 0; ko < 2; ++ko) {
      bf16x8 af[4], bfr[4];
#pragma unroll
      for (int i = 0; i < 4; ++i) {
        int ar = wr * 64 + i * 16 + (lane & 15);
        int as = (ko * 4 + (lane >> 4)) ^ (ar & 7);
        af[i] = *(const bf16x8*)&As[ar * 64 + as * 8];
        int br = wc * 64 + i * 16 + (lane & 15);
        int bs = (ko * 4 + (lane >> 4)) ^ (br & 7);
        bfr[i] = *(const bf16x8*)&Bs[br * 64 + bs * 8];
      }
#pragma unroll
      for (int mi = 0; mi < 4; ++mi)
#pragma unroll
        for (int ni = 0; ni < 4; ++ni)
          acc[mi][ni] = __builtin_amdgcn_mfma_f32_16x16x32_bf16(af[mi], bfr[ni], acc[mi][ni], 0, 0, 0);
    }
    __syncthreads();
  }

  // epilogue: C/D layout col = lane&15, row = (lane>>4)*4 + j  [m89-verified]
  const int rg = (lane >> 4) * 4;
  const int cn = lane & 15;
#pragma unroll
  for (int mi = 0; mi < 4; ++mi) {
#pragma unroll
    for (int j = 0; j < 4; ++j) {
      int m = bm + wr * 64 + mi * 16 + rg + j;
      if (m < M) {
        float di = dinv[m];
#pragma unroll
        for (int ni = 0; ni < 4; ++ni) {
          int n = bn + wc * 64 + ni * 16 + cn;
          H[(size_t)m * N + n] = f2bf_rne(acc[mi][ni][j] * di);
        }
      }
    }
  }
}

// ---------------- agg1: pull aggregation + bias + ReLU + fused LN stats ----------------
// Hs = bf16x2 rows, pre-scaled by dinv[src].
// out[d] = relu( dinv[d] * ( sum_e Hs[src_e] + Hs[d] ) + bias )
template <int F>
__global__ __launch_bounds__(256) void agg_kernel(const unsigned int* __restrict__ Hs,
                                                  const int* __restrict__ row_ptr,
                                                  const int* __restrict__ csr_src,
                                                  const float* __restrict__ dinv,
                                                  const float* __restrict__ bias,
                                                  float* __restrict__ out, int n,
                                                  double* __restrict__ psum,
                                                  double* __restrict__ psq) {
  constexpr int LPN = F / 2;           // lanes per node (each lane = 2 features)
  constexpr int NODES = 256 / LPN;
  int node = blockIdx.x * NODES + threadIdx.x / LPN;
  int f2 = threadIdx.x % LPN;
  float r0 = 0.f, r1 = 0.f;
  if (node < n) {
    unsigned int su = Hs[(size_t)node * LPN + f2];   // self term (already dinv[d]-scaled)
    float a0 = bf_lo(su), a1 = bf_hi(su);
    float b0 = 0.f, b1 = 0.f, c0 = 0.f, c1 = 0.f, d0 = 0.f, d1 = 0.f;
    int e = row_ptr[node];
    const int e1 = row_ptr[node + 1];
    for (; e + 4 <= e1; e += 4) {
      int s0 = csr_src[e], s1 = csr_src[e + 1], s2 = csr_src[e + 2], s3 = csr_src[e + 3];
      unsigned int u0 = Hs[(size_t)s0 * LPN + f2];
      unsigned int u1 = Hs[(size_t)s1 * LPN + f2];
      unsigned int u2 = Hs[(size_t)s2 * LPN + f2];
      unsigned int u3 = Hs[(size_t)s3 * LPN + f2];
      a0 += bf_lo(u0); a1 += bf_hi(u0);
      b0 += bf_lo(u1); b1 += bf_hi(u1);
      c0 += bf_lo(u2); c1 += bf_hi(u2);
      d0 += bf_lo(u3); d1 += bf_hi(u3);
    }
    for (; e < e1; ++e) {
      int s0 = csr_src[e];
      unsigned int u0 = Hs[(size_t)s0 * LPN + f2];
      a0 += bf_lo(u0); a1 += bf_hi(u0);
    }
    float di = dinv[node];
    float2 bv = *(const float2*)&bias[2 * f2];
    r0 = fmaxf(fmaf(di, (a0 + b0) + (c0 + d0), bv.x), 0.f);
    r1 = fmaxf(fmaf(di, (a1 + b1) + (c1 + d1), bv.y), 0.f);
    float2 o = make_float2(r0, r1);
    *(float2*)&out[(size_t)node * F + 2 * f2] = o;
  }
  __shared__ double sh[256], sh2[256];
  sh[threadIdx.x] = (double)r0 + (double)r1;
  sh2[threadIdx.x] = (double)r0 * r0 + (double)r1 * r1;
  __syncthreads();
  for (int off = 128; off > 0; off >>= 1) {
    if ((int)threadIdx.x < off) { sh[threadIdx.x] += sh[threadIdx.x + off]; sh2[threadIdx.x] += sh2[threadIdx.x + off]; }
    __syncthreads();
  }
  if (threadIdx.x == 0) { psum[blockIdx.x] = sh[0]; psq[blockIdx.x] = sh2[0]; }
}

// ---------------- agg2: aggregation + bias + ReLU + per-block column sums ----------------
// c2 is never materialized: its only consumer is the final LN+mean-pool, which needs
// per-column sums and the global sum of squares. NITER node-groups per block.
#define AGG2_NITER 8
__global__ __launch_bounds__(256) void agg_colstats(const unsigned int* __restrict__ Hs,
                                                    const int* __restrict__ row_ptr,
                                                    const int* __restrict__ csr_src,
                                                    const float* __restrict__ dinv,
                                                    const float* __restrict__ bias,
                                                    int n,
                                                    double* __restrict__ colpart,
                                                    double* __restrict__ qpart) {
  constexpr int F = OUT_F;
  constexpr int LPN = F / 2;           // 64 lanes per node
  constexpr int NODES = 256 / LPN;     // 4 nodes per group
  const int f2 = threadIdx.x % LPN;
  const int grp = threadIdx.x / LPN;   // 0..3
  float2 bv = *(const float2*)&bias[2 * f2];
  double cs0 = 0.0, cs1 = 0.0, q = 0.0;
  for (int it = 0; it < AGG2_NITER; ++it) {
    int node = (blockIdx.x * AGG2_NITER + it) * NODES + grp;
    if (node < n) {
      unsigned int su = Hs[(size_t)node * LPN + f2];
      float a0 = bf_lo(su), a1 = bf_hi(su);
      float b0 = 0.f, b1 = 0.f, c0 = 0.f, c1 = 0.f, d0 = 0.f, d1 = 0.f;
      int e = row_ptr[node];
      const int e1 = row_ptr[node + 1];
      for (; e + 4 <= e1; e += 4) {
        int s0 = csr_src[e], s1 = csr_src[e + 1], s2 = csr_src[e + 2], s3 = csr_src[e + 3];
        unsigned int u0 = Hs[(size_t)s0 * LPN + f2];
        unsigned int u1 = Hs[(size_t)s1 * LPN + f2];
        unsigned int u2 = Hs[(size_t)s2 * LPN + f2];
        unsigned int u3 = Hs[(size_t)s3 * LPN + f2];
        a0 += bf_lo(u0); a1 += bf_hi(u0);
        b0 += bf_lo(u1); b1 += bf_hi(u1);
        c0 += bf_lo(u2); c1 += bf_hi(u2);
        d0 += bf_lo(u3); d1 += bf_hi(u3);
      }
      for (; e < e1; ++e) {
        int s0 = csr_src[e];
        unsigned int u0 = Hs[(size_t)s0 * LPN + f2];
        a0 += bf_lo(u0); a1 += bf_hi(u0);
      }
      float di = dinv[node];
      float r0 = fmaxf(fmaf(di, (a0 + b0) + (c0 + d0), bv.x), 0.f);
      float r1 = fmaxf(fmaf(di, (a1 + b1) + (c1 + d1), bv.y), 0.f);
      cs0 += (double)r0; cs1 += (double)r1;
      q += (double)r0 * r0 + (double)r1 * r1;
    }
  }
  __shared__ double sh0[256], sh1[256], shq[256];
  sh0[threadIdx.x] = cs0; sh1[threadIdx.x] = cs1; shq[threadIdx.x] = q;
  __syncthreads();
  // reduce the 4 node-groups onto grp 0
  if (grp == 0) {
#pragma unroll
    for (int g = 1; g < NODES; ++g) {
      sh0[threadIdx.x] += sh0[threadIdx.x + g * LPN];
      sh1[threadIdx.x] += sh1[threadIdx.x + g * LPN];
    }
    colpart[(size_t)blockIdx.x * F + 2 * f2]     = sh0[threadIdx.x];
    colpart[(size_t)blockIdx.x * F + 2 * f2 + 1] = sh1[threadIdx.x];
  }
  for (int off = 128; off > 0; off >>= 1) {
    if ((int)threadIdx.x < off) shq[threadIdx.x] += shq[threadIdx.x + off];
    __syncthreads();
  }
  if (threadIdx.x == 0) qpart[blockIdx.x] = shq[0];
}

// ---------------- final LN + mean pool (collapsed) ----------------
__global__ __launch_bounds__(1024) void final_kernel(const double* __restrict__ colpart,
                                                     const double* __restrict__ qpart, int B, int n,
                                                     const float* __restrict__ lnw,
                                                     const float* __restrict__ lnb,
                                                     float* __restrict__ out) {
  __shared__ double shc[1024], shq[1024];
  const int tid = threadIdx.x;
  const int col = tid & 127, slice = tid >> 7;  // 8 slices
  double s = 0.0;
  for (int b = slice; b < B; b += 8) s += colpart[(size_t)b * OUT_F + col];
  double q = 0.0;
  for (int b = tid; b < B; b += 1024) q += qpart[b];
  shc[tid] = s; shq[tid] = q;
  __syncthreads();
  for (int off = 512; off > 0; off >>= 1) {
    if (tid < off) shq[tid] += shq[tid + off];
    __syncthreads();
  }
  double cs = 0.0;
  if (tid < 128) {
#pragma unroll
    for (int sl = 0; sl < 8; ++sl) cs += shc[sl * 128 + col];
  }
  double qtot = shq[0];
  __syncthreads();
  shc[tid] = (tid < 128) ? cs : 0.0;
  __syncthreads();
  for (int off = 64; off > 0; off >>= 1) {
    if (tid < off) shc[tid] += shc[tid + off];
    __syncthreads();
  }
  if (tid < 128) {
    double cnt = (double)n * (double)OUT_F;
    double mean = shc[0] / cnt;
    double var = qtot / cnt - mean * mean;
    double inv = 1.0 / sqrt(var + 1e-5);
    double colmean = cs / (double)n;
    out[tid] = (float)((colmean - mean) * inv * (double)lnw[tid] + (double)lnb[tid]);
  }
}

// ---------------- launch ----------------
extern "C" void kernel_launch(void* const* d_in, const int* in_sizes, int n_in,
                              void* d_out, int out_size, void* d_ws, size_t ws_size,
                              hipStream_t stream) {
  const float* x   = (const float*)d_in[0];
  const int*  ei   = (const int*)d_in[1];
  const float* W1  = (const float*)d_in[2];
  const float* b1  = (const float*)d_in[3];
  const float* W2  = (const float*)d_in[4];
  const float* b2  = (const float*)d_in[5];
  const float* ln0w = (const float*)d_in[6];
  const float* ln0b = (const float*)d_in[7];
  const float* ln1w = (const float*)d_in[8];
  const float* ln1b = (const float*)d_in[9];
  const float* ln2w = (const float*)d_in[10];
  const float* ln2b = (const float*)d_in[11];

  const int N = in_sizes[0] / IN_F;
  const int E = in_sizes[1] / 2;
  const int Mpad = ((N + 127) / 128) * 128;
  const int* src = ei;
  const int* dst = ei + E;

  const int agg1_blocks = (N + 1) / 2;                      // 2 nodes/block at F=256
  const int agg2_blocks = (N + 4 * AGG2_NITER - 1) / (4 * AGG2_NITER);  // 32 nodes/block

  char* ws = (char*)d_ws;
  size_t off = 0;
  auto alloc = [&](size_t bytes) -> void* {
    void* p = ws + off;
    off += (bytes + 255) & ~(size_t)255;
    return p;
  };
  int*    counts  = (int*)alloc((size_t)N * 4);        // zeroed
  int*    fill    = (int*)alloc((size_t)N * 4);        // zeroed
  size_t zero_bytes = off;
  float*  dinv    = (float*)alloc((size_t)N * 4);
  int*    row_ptr = (int*)alloc((size_t)(N + 8) * 4);
  int*    csr_src = (int*)alloc((size_t)E * 4);
  int     nb_max  = agg1_blocks > G_STATS ? agg1_blocks : G_STATS;
  double* psum    = (double*)alloc((size_t)nb_max * 8);
  double* psq     = (double*)alloc((size_t)nb_max * 8);
  double* colpart = (double*)alloc((size_t)agg2_blocks * OUT_F * 8);
  double* qpart   = (double*)alloc((size_t)agg2_blocks * 8);
  float*  s0      = (float*)alloc(IN_F * 4);
  float*  t0      = (float*)alloc(IN_F * 4);
  float*  s1      = (float*)alloc(HID_F * 4);
  float*  t1      = (float*)alloc(HID_F * 4);
  u16*    Wt1     = (u16*)alloc((size_t)HID_F * IN_F * 2);
  u16*    Wt2     = (u16*)alloc((size_t)OUT_F * HID_F * 2);
  u16*    h1      = (u16*)alloc((size_t)N * HID_F * 2);     // 25.6 MB; reused for h2
  float*  c1      = (float*)alloc((size_t)N * HID_F * 4);   // 51.2 MB
  u16*    h2 = h1;     // h1 dead after agg1

  hipMemsetAsync(ws, 0, zero_bytes, stream);

  // graph prep
  count_kernel<<<1024, 256, 0, stream>>>(dst, E, counts);
  dinv_kernel<<<(N + 255) / 256, 256, 0, stream>>>(counts, dinv, N);
  scan_kernel<<<1, 1024, 0, stream>>>(counts, row_ptr, N);
  scatter_kernel<<<1024, 256, 0, stream>>>(src, dst, E, row_ptr, fill, csr_src);

  // weight transposes (bf16)
  wt_kernel<<<dim3(HID_F / 32, IN_F / 32), 256, 0, stream>>>(W1, Wt1, IN_F, HID_F);
  wt_kernel<<<dim3(OUT_F / 32, HID_F / 32), 256, 0, stream>>>(W2, Wt2, HID_F, OUT_F);

  // LN0 stats (over x) -> fused scale/shift
  stats_partial<<<G_STATS, 256, 0, stream>>>((const float4*)x, (long)N * IN_F / 4, psum, psq);
  finalize_ln<<<1, 512, 0, stream>>>(psum, psq, G_STATS, 1.0 / ((double)N * IN_F), ln0w, ln0b, s0, t0, IN_F);

  // conv1: h1 = bf16(dinv * (LN0(x) @ W1)) ; agg -> c1 (bias+relu+LN1 stats fused)
  gemm_ln_mfma<<<dim3(Mpad / 128, HID_F / 128), 256, 0, stream>>>(x, Wt1, N, IN_F, HID_F, s0, t0, dinv, h1);
  agg_kernel<HID_F><<<agg1_blocks, 256, 0, stream>>>((const unsigned int*)h1, row_ptr, csr_src,
                                                     dinv, b1, c1, N, psum, psq);
  finalize_ln<<<1, 512, 0, stream>>>(psum, psq, agg1_blocks, 1.0 / ((double)N * HID_F), ln1w, ln1b, s1, t1, HID_F);

  // conv2: h2 = bf16(dinv * (LN1(c1) @ W2)) ; agg2 with fused column stats (no c2)
  gemm_ln_mfma<<<dim3(Mpad / 128, OUT_F / 128), 256, 0, stream>>>(c1, Wt2, N, HID_F, OUT_F, s1, t1, dinv, h2);
  agg_colstats<<<agg2_blocks, 256, 0, stream>>>((const unsigned int*)h2, row_ptr, csr_src,
                                                dinv, b2, N, colpart, qpart);

  // final LN + mean pool
  final_kernel<<<1, 1024, 0, stream>>>(colpart, qpart, agg2_blocks, N, ln2w, ln2b, (float*)d_out);
}

// Round 13
// 650.713 us; speedup vs baseline: 1.9920x; 1.0781x over previous
//
#include <hip/hip_runtime.h>

typedef unsigned short u16;
typedef __attribute__((ext_vector_type(8))) short bf16x8;
typedef __attribute__((ext_vector_type(4))) float f32x4;

// Problem constants
#define IN_F  512
#define HID_F 256
#define OUT_F 128
#define G_STATS 1024   // blocks for input stats partial reduction

// ---------------- helpers ----------------
__device__ inline u16 f2bf_rne(float f) {
  unsigned int u = __float_as_uint(f);
  unsigned int r = (u + 0x7fffu + ((u >> 16) & 1u)) >> 16;
  return (u16)r;
}
__device__ inline unsigned int pack_bf2(float lo, float hi) {
  return (unsigned int)f2bf_rne(lo) | ((unsigned int)f2bf_rne(hi) << 16);
}
__device__ inline float bf_lo(unsigned int u) { return __uint_as_float(u << 16); }
__device__ inline float bf_hi(unsigned int u) { return __uint_as_float(u & 0xffff0000u); }

// ---------------- graph prep ----------------
__global__ __launch_bounds__(256) void count_kernel(const int* __restrict__ dst, int E,
                                                    int* __restrict__ counts) {
  int stride = gridDim.x * blockDim.x;
  for (int i = blockIdx.x * blockDim.x + threadIdx.x; i < E; i += stride)
    atomicAdd(&counts[dst[i]], 1);
}

__global__ __launch_bounds__(256) void dinv_kernel(const int* __restrict__ counts,
                                                   float* __restrict__ dinv, int n) {
  int i = blockIdx.x * blockDim.x + threadIdx.x;
  if (i < n) dinv[i] = rsqrtf((float)counts[i] + 1.0f);  // +1 self-loop, always > 0
}

// Exclusive scan of counts[n] -> row_ptr[n+1], single block of 1024 threads.
// Coalesced int4 loads + aligned int4 stores (row_ptr[i] = exclusive prefix).
__global__ __launch_bounds__(1024) void scan_kernel(const int* __restrict__ counts,
                                                    int* __restrict__ row_ptr, int n) {
  __shared__ int wsum[16];
  __shared__ int s_carry, s_total;
  const int tid = threadIdx.x;
  const int lane = tid & 63, wid = tid >> 6;
  if (tid == 0) s_carry = 0;
  __syncthreads();
  const int PER = 8, CH = 1024 * PER;
  for (int base = 0; base < n; base += CH) {
    int i0 = base + tid * PER;
    int v[PER];
    int s = 0;
    if (i0 + PER <= n) {
      int4 a = *(const int4*)&counts[i0];
      int4 b = *(const int4*)&counts[i0 + 4];
      int c[8] = {a.x, a.y, a.z, a.w, b.x, b.y, b.z, b.w};
#pragma unroll
      for (int j = 0; j < 8; ++j) { s += c[j]; v[j] = s; }
    } else {
#pragma unroll
      for (int j = 0; j < PER; ++j) { int i = i0 + j; int c = (i < n) ? counts[i] : 0; s += c; v[j] = s; }
    }
    int ts = s;
#pragma unroll
    for (int off = 1; off < 64; off <<= 1) {
      int o = __shfl_up(ts, off, 64);
      if (lane >= off) ts += o;
    }
    if (lane == 63) wsum[wid] = ts;
    __syncthreads();
    if (tid == 0) {
      int c = 0;
#pragma unroll
      for (int w = 0; w < 16; ++w) { int t = wsum[w]; wsum[w] = c; c += t; }
      s_total = c;
    }
    __syncthreads();
    int base_excl = s_carry + wsum[wid] + (ts - s);
    if (i0 + PER <= n) {
      int4 o0 = make_int4(base_excl, base_excl + v[0], base_excl + v[1], base_excl + v[2]);
      int4 o1 = make_int4(base_excl + v[3], base_excl + v[4], base_excl + v[5], base_excl + v[6]);
      *(int4*)&row_ptr[i0] = o0;
      *(int4*)&row_ptr[i0 + 4] = o1;
    } else {
      for (int j = 0; j < PER; ++j) { int i = i0 + j; if (i < n) row_ptr[i] = base_excl + (j ? v[j - 1] : 0); }
    }
    __syncthreads();
    if (tid == 0) s_carry += s_total;
    __syncthreads();
  }
  if (tid == 0) row_ptr[n] = s_carry;
}

__global__ __launch_bounds__(256) void scatter_kernel(const int* __restrict__ src,
                                                      const int* __restrict__ dst, int E,
                                                      const int* __restrict__ row_ptr,
                                                      int* __restrict__ fill,
                                                      int* __restrict__ csr_src) {
  int stride = gridDim.x * blockDim.x;
  for (int i = blockIdx.x * blockDim.x + threadIdx.x; i < E; i += stride) {
    int d = dst[i];
    int p = row_ptr[d] + atomicAdd(&fill[d], 1);
    csr_src[p] = src[i];
  }
}

// ---------------- LN stats over x ----------------
__global__ __launch_bounds__(256) void stats_partial(const float4* __restrict__ x, long n4,
                                                     double* __restrict__ psum,
                                                     double* __restrict__ psq) {
  double s = 0.0, q = 0.0;
  long stride = (long)gridDim.x * 256;
  for (long i = (long)blockIdx.x * 256 + threadIdx.x; i < n4; i += stride) {
    float4 v = x[i];
    s += (double)((v.x + v.y) + (v.z + v.w));
    q += (double)v.x * v.x + (double)v.y * v.y + (double)v.z * v.z + (double)v.w * v.w;
  }
  __shared__ double sh[256], sh2[256];
  sh[threadIdx.x] = s; sh2[threadIdx.x] = q;
  __syncthreads();
  for (int off = 128; off > 0; off >>= 1) {
    if (threadIdx.x < off) { sh[threadIdx.x] += sh[threadIdx.x + off]; sh2[threadIdx.x] += sh2[threadIdx.x + off]; }
    __syncthreads();
  }
  if (threadIdx.x == 0) { psum[blockIdx.x] = sh[0]; psq[blockIdx.x] = sh2[0]; }
}

// Reduce partials, then write per-channel fused scale/shift: a = x*s[k] + t[k]
__global__ __launch_bounds__(512) void finalize_ln(const double* __restrict__ psum,
                            const double* __restrict__ psq,
                            int nb, double inv_count,
                            const float* __restrict__ lnw, const float* __restrict__ lnb,
                            float* __restrict__ s, float* __restrict__ t, int C) {
  double a = 0.0, b = 0.0;
  for (int i = threadIdx.x; i < nb; i += blockDim.x) { a += psum[i]; b += psq[i]; }
  __shared__ double sa[512], sb[512];
  sa[threadIdx.x] = a; sb[threadIdx.x] = b;
  __syncthreads();
  for (int off = blockDim.x >> 1; off > 0; off >>= 1) {
    if ((int)threadIdx.x < off) { sa[threadIdx.x] += sa[threadIdx.x + off]; sb[threadIdx.x] += sb[threadIdx.x + off]; }
    __syncthreads();
  }
  double mean = sa[0] * inv_count;
  double var  = sb[0] * inv_count - mean * mean;
  double inv  = 1.0 / sqrt(var + 1e-5);
  int k = threadIdx.x;
  if (k < C) {
    double sc = inv * (double)lnw[k];
    s[k] = (float)sc;
    t[k] = (float)((double)lnb[k] - mean * sc);
  }
}

// ---------------- weight transpose+convert: W[K][N] f32 -> Wt[N][K] bf16 ----------------
__global__ __launch_bounds__(256) void wt_kernel(const float* __restrict__ W,
                                                 u16* __restrict__ Wt, int K, int N) {
  __shared__ float tile[32][33];
  int n0 = blockIdx.x * 32, k0 = blockIdx.y * 32;
  int tx = threadIdx.x & 31, ty = threadIdx.x >> 5;  // ty 0..7
  for (int r = ty; r < 32; r += 8) tile[r][tx] = W[(size_t)(k0 + r) * N + n0 + tx];
  __syncthreads();
  for (int r = ty; r < 32; r += 8) Wt[(size_t)(n0 + r) * K + k0 + tx] = f2bf_rne(tile[tx][r]);
}

// ---------------- MFMA bf16 GEMM with fused LN on A: H = bf16(dinv[m]*(LN(X) @ Wt^T)) ----
// X [M][K] fp32 row-major; LN fused as x*s[k]+t[k], bf16-converted during staging.
// Wt [N][K] bf16 row-major (i.e. W^T).
// Template WN = waves in N: block = 2*WN waves (128*WN threads), tile 128 x (64*WN).
// This round only WN=2 (256 threads, 128x128 tile — hardware-proven config) is used;
// WN=4 retried in isolation next round after container-failure diagnosis.
// LDS XOR-swizzle: 16B slot ^= (row&7) on both ds_write and ds_read.
template <int WN>
__global__ __launch_bounds__(128 * WN) void gemm_ln_mfma(const float* __restrict__ X,
                                                         const u16* __restrict__ Bt,
                                                         int M, int K, int N,
                                                         const float* __restrict__ s,
                                                         const float* __restrict__ t,
                                                         const float* __restrict__ dinv,
                                                         u16* __restrict__ H) {
  constexpr int BN = WN * 64;
  constexpr int THREADS = 128 * WN;
  __shared__ u16 As[128 * 64];
  __shared__ u16 Bs[BN * 64];
  const int tid = threadIdx.x;
  const int lane = tid & 63;
  const int wid = tid >> 6;          // 0 .. 2*WN-1
  const int wr = wid / WN;           // 0..1
  const int wc = wid % WN;           // 0..WN-1
  const int bm = blockIdx.x * 128;
  const int bn = blockIdx.y * BN;

  f32x4 acc[4][4] = {};

  for (int k0 = 0; k0 < K; k0 += 64) {
    // A tile: 128x64 bf16 = 1024 x 16B slots
#pragma unroll
    for (int i = 0; i < 1024 / THREADS; ++i) {
      int g = i * THREADS + tid;
      int row = g >> 3;
      int slot = g & 7;
      int gk = k0 + slot * 8;
      int wsi = row * 64 + ((slot ^ (row & 7)) * 8);
      int gm = bm + row;
      uint4 o = make_uint4(0u, 0u, 0u, 0u);
      if (gm < M) {
        float4 v0 = *(const float4*)&X[(size_t)gm * K + gk];
        float4 v1 = *(const float4*)&X[(size_t)gm * K + gk + 4];
        float4 sA = *(const float4*)&s[gk];
        float4 sB = *(const float4*)&s[gk + 4];
        float4 tA = *(const float4*)&t[gk];
        float4 tB = *(const float4*)&t[gk + 4];
        o.x = pack_bf2(fmaf(v0.x, sA.x, tA.x), fmaf(v0.y, sA.y, tA.y));
        o.y = pack_bf2(fmaf(v0.z, sA.z, tA.z), fmaf(v0.w, sA.w, tA.w));
        o.z = pack_bf2(fmaf(v1.x, sB.x, tB.x), fmaf(v1.y, sB.y, tB.y));
        o.w = pack_bf2(fmaf(v1.z, sB.z, tB.z), fmaf(v1.w, sB.w, tB.w));
      }
      *(uint4*)&As[wsi] = o;
    }
    // B tile: BNx64 bf16 = BN*8 x 16B slots
#pragma unroll
    for (int i = 0; i < (BN * 8) / THREADS; ++i) {
      int g = i * THREADS + tid;
      int row = g >> 3;
      int slot = g & 7;
      int wsi = row * 64 + ((slot ^ (row & 7)) * 8);
      uint4 vb = *(const uint4*)&Bt[(size_t)(bn + row) * K + k0 + slot * 8];
      *(uint4*)&Bs[wsi] = vb;
    }
    __syncthreads();
#pragma unroll
    for (int ko = 0; ko < 2; ++ko) {
      bf16x8 af[4], bfr[4];
#pragma unroll
      for (int i = 0; i < 4; ++i) {
        int ar = wr * 64 + i * 16 + (lane & 15);
        int as = (ko * 4 + (lane >> 4)) ^ (ar & 7);
        af[i] = *(const bf16x8*)&As[ar * 64 + as * 8];
        int br = wc * 64 + i * 16 + (lane & 15);
        int bs = (ko * 4 + (lane >> 4)) ^ (br & 7);
        bfr[i] = *(const bf16x8*)&Bs[br * 64 + bs * 8];
      }
#pragma unroll
      for (int mi = 0; mi < 4; ++mi)
#pragma unroll
        for (int ni = 0; ni < 4; ++ni)
          acc[mi][ni] = __builtin_amdgcn_mfma_f32_16x16x32_bf16(af[mi], bfr[ni], acc[mi][ni], 0, 0, 0);
    }
    __syncthreads();
  }

  // epilogue: C/D layout col = lane&15, row = (lane>>4)*4 + j  [m89-verified]
  const int rg = (lane >> 4) * 4;
  const int cn = lane & 15;
#pragma unroll
  for (int mi = 0; mi < 4; ++mi) {
#pragma unroll
    for (int j = 0; j < 4; ++j) {
      int m = bm + wr * 64 + mi * 16 + rg + j;
      if (m < M) {
        float di = dinv[m];
#pragma unroll
        for (int ni = 0; ni < 4; ++ni) {
          int n = bn + wc * 64 + ni * 16 + cn;
          H[(size_t)m * N + n] = f2bf_rne(acc[mi][ni][j] * di);
        }
      }
    }
  }
}

// ---------------- agg1: pull aggregation + bias + ReLU + fused LN stats ----------------
// Hs = bf16x2 rows, pre-scaled by dinv[src].
// out[d] = relu( dinv[d] * ( sum_e Hs[src_e] + Hs[d] ) + bias )
template <int F>
__global__ __launch_bounds__(256) void agg_kernel(const unsigned int* __restrict__ Hs,
                                                  const int* __restrict__ row_ptr,
                                                  const int* __restrict__ csr_src,
                                                  const float* __restrict__ dinv,
                                                  const float* __restrict__ bias,
                                                  float* __restrict__ out, int n,
                                                  double* __restrict__ psum,
                                                  double* __restrict__ psq) {
  constexpr int LPN = F / 2;           // lanes per node (each lane = 2 features)
  constexpr int NODES = 256 / LPN;
  int node = blockIdx.x * NODES + threadIdx.x / LPN;
  int f2 = threadIdx.x % LPN;
  float r0 = 0.f, r1 = 0.f;
  if (node < n) {
    unsigned int su = Hs[(size_t)node * LPN + f2];   // self term (already dinv[d]-scaled)
    float a0 = bf_lo(su), a1 = bf_hi(su);
    float b0 = 0.f, b1 = 0.f, c0 = 0.f, c1 = 0.f, d0 = 0.f, d1 = 0.f;
    int e = row_ptr[node];
    const int e1 = row_ptr[node + 1];
    for (; e + 4 <= e1; e += 4) {
      int s0 = csr_src[e], s1 = csr_src[e + 1], s2 = csr_src[e + 2], s3 = csr_src[e + 3];
      unsigned int u0 = Hs[(size_t)s0 * LPN + f2];
      unsigned int u1 = Hs[(size_t)s1 * LPN + f2];
      unsigned int u2 = Hs[(size_t)s2 * LPN + f2];
      unsigned int u3 = Hs[(size_t)s3 * LPN + f2];
      a0 += bf_lo(u0); a1 += bf_hi(u0);
      b0 += bf_lo(u1); b1 += bf_hi(u1);
      c0 += bf_lo(u2); c1 += bf_hi(u2);
      d0 += bf_lo(u3); d1 += bf_hi(u3);
    }
    for (; e < e1; ++e) {
      int s0 = csr_src[e];
      unsigned int u0 = Hs[(size_t)s0 * LPN + f2];
      a0 += bf_lo(u0); a1 += bf_hi(u0);
    }
    float di = dinv[node];
    float2 bv = *(const float2*)&bias[2 * f2];
    r0 = fmaxf(fmaf(di, (a0 + b0) + (c0 + d0), bv.x), 0.f);
    r1 = fmaxf(fmaf(di, (a1 + b1) + (c1 + d1), bv.y), 0.f);
    float2 o = make_float2(r0, r1);
    *(float2*)&out[(size_t)node * F + 2 * f2] = o;
  }
  __shared__ double sh[256], sh2[256];
  sh[threadIdx.x] = (double)r0 + (double)r1;
  sh2[threadIdx.x] = (double)r0 * r0 + (double)r1 * r1;
  __syncthreads();
  for (int off = 128; off > 0; off >>= 1) {
    if ((int)threadIdx.x < off) { sh[threadIdx.x] += sh[threadIdx.x + off]; sh2[threadIdx.x] += sh2[threadIdx.x + off]; }
    __syncthreads();
  }
  if (threadIdx.x == 0) { psum[blockIdx.x] = sh[0]; psq[blockIdx.x] = sh2[0]; }
}

// ---------------- agg2: aggregation + bias + ReLU + per-block column sums ----------------
// c2 never materialized. NITER=2 -> ~6250 blocks (TLP to hide gather latency).
#define AGG2_NITER 2
__global__ __launch_bounds__(256) void agg_colstats(const unsigned int* __restrict__ Hs,
                                                    const int* __restrict__ row_ptr,
                                                    const int* __restrict__ csr_src,
                                                    const float* __restrict__ dinv,
                                                    const float* __restrict__ bias,
                                                    int n,
                                                    double* __restrict__ colpart,
                                                    double* __restrict__ qpart) {
  constexpr int F = OUT_F;
  constexpr int LPN = F / 2;           // 64 lanes per node
  constexpr int NODES = 256 / LPN;     // 4 nodes per group
  const int f2 = threadIdx.x % LPN;
  const int grp = threadIdx.x / LPN;   // 0..3
  float2 bv = *(const float2*)&bias[2 * f2];
  double cs0 = 0.0, cs1 = 0.0, q = 0.0;
  for (int it = 0; it < AGG2_NITER; ++it) {
    int node = (blockIdx.x * AGG2_NITER + it) * NODES + grp;
    if (node < n) {
      unsigned int su = Hs[(size_t)node * LPN + f2];
      float a0 = bf_lo(su), a1 = bf_hi(su);
      float b0 = 0.f, b1 = 0.f, c0 = 0.f, c1 = 0.f, d0 = 0.f, d1 = 0.f;
      int e = row_ptr[node];
      const int e1 = row_ptr[node + 1];
      for (; e + 4 <= e1; e += 4) {
        int s0 = csr_src[e], s1 = csr_src[e + 1], s2 = csr_src[e + 2], s3 = csr_src[e + 3];
        unsigned int u0 = Hs[(size_t)s0 * LPN + f2];
        unsigned int u1 = Hs[(size_t)s1 * LPN + f2];
        unsigned int u2 = Hs[(size_t)s2 * LPN + f2];
        unsigned int u3 = Hs[(size_t)s3 * LPN + f2];
        a0 += bf_lo(u0); a1 += bf_hi(u0);
        b0 += bf_lo(u1); b1 += bf_hi(u1);
        c0 += bf_lo(u2); c1 += bf_hi(u2);
        d0 += bf_lo(u3); d1 += bf_hi(u3);
      }
      for (; e < e1; ++e) {
        int s0 = csr_src[e];
        unsigned int u0 = Hs[(size_t)s0 * LPN + f2];
        a0 += bf_lo(u0); a1 += bf_hi(u0);
      }
      float di = dinv[node];
      float r0 = fmaxf(fmaf(di, (a0 + b0) + (c0 + d0), bv.x), 0.f);
      float r1 = fmaxf(fmaf(di, (a1 + b1) + (c1 + d1), bv.y), 0.f);
      cs0 += (double)r0; cs1 += (double)r1;
      q += (double)r0 * r0 + (double)r1 * r1;
    }
  }
  __shared__ double sh0[256], sh1[256], shq[256];
  sh0[threadIdx.x] = cs0; sh1[threadIdx.x] = cs1; shq[threadIdx.x] = q;
  __syncthreads();
  // reduce the 4 node-groups onto grp 0
  if (grp == 0) {
#pragma unroll
    for (int g = 1; g < NODES; ++g) {
      sh0[threadIdx.x] += sh0[threadIdx.x + g * LPN];
      sh1[threadIdx.x] += sh1[threadIdx.x + g * LPN];
    }
    colpart[(size_t)blockIdx.x * F + 2 * f2]     = sh0[threadIdx.x];
    colpart[(size_t)blockIdx.x * F + 2 * f2 + 1] = sh1[threadIdx.x];
  }
  for (int off = 128; off > 0; off >>= 1) {
    if ((int)threadIdx.x < off) shq[threadIdx.x] += shq[threadIdx.x + off];
    __syncthreads();
  }
  if (threadIdx.x == 0) qpart[blockIdx.x] = shq[0];
}

// ---------------- column reduce: colpart[B][128] -> colsum[128], qpart[B] -> colsum[128+] ----
__global__ __launch_bounds__(256) void colred_kernel(const double* __restrict__ colpart,
                                                     const double* __restrict__ qpart, int B,
                                                     double* __restrict__ colsum) {
  const int b = blockIdx.x;   // 0..127 = columns, 128 = qpart
  double s = 0.0;
  if (b < OUT_F) {
    for (int i = threadIdx.x; i < B; i += 256) s += colpart[(size_t)i * OUT_F + b];
  } else {
    for (int i = threadIdx.x; i < B; i += 256) s += qpart[i];
  }
  __shared__ double sh[256];
  sh[threadIdx.x] = s;
  __syncthreads();
  for (int off = 128; off > 0; off >>= 1) {
    if ((int)threadIdx.x < off) sh[threadIdx.x] += sh[threadIdx.x + off];
    __syncthreads();
  }
  if (threadIdx.x == 0) colsum[b] = sh[0];
}

// ---------------- final LN + mean pool ----------------
__global__ __launch_bounds__(128) void final_kernel(const double* __restrict__ colsum, int n,
                                                    const float* __restrict__ lnw,
                                                    const float* __restrict__ lnb,
                                                    float* __restrict__ out) {
  const int c = threadIdx.x;
  double cs = colsum[c];
  __shared__ double sh[128];
  sh[c] = cs;
  __syncthreads();
  for (int off = 64; off > 0; off >>= 1) {
    if (c < off) sh[c] += sh[c + off];
    __syncthreads();
  }
  double cnt = (double)n * (double)OUT_F;
  double mean = sh[0] / cnt;
  double var = colsum[OUT_F] / cnt - mean * mean;
  double inv = 1.0 / sqrt(var + 1e-5);
  double colmean = cs / (double)n;
  out[c] = (float)((colmean - mean) * inv * (double)lnw[c] + (double)lnb[c]);
}

// ---------------- launch ----------------
extern "C" void kernel_launch(void* const* d_in, const int* in_sizes, int n_in,
                              void* d_out, int out_size, void* d_ws, size_t ws_size,
                              hipStream_t stream) {
  const float* x   = (const float*)d_in[0];
  const int*  ei   = (const int*)d_in[1];
  const float* W1  = (const float*)d_in[2];
  const float* b1  = (const float*)d_in[3];
  const float* W2  = (const float*)d_in[4];
  const float* b2  = (const float*)d_in[5];
  const float* ln0w = (const float*)d_in[6];
  const float* ln0b = (const float*)d_in[7];
  const float* ln1w = (const float*)d_in[8];
  const float* ln1b = (const float*)d_in[9];
  const float* ln2w = (const float*)d_in[10];
  const float* ln2b = (const float*)d_in[11];

  const int N = in_sizes[0] / IN_F;
  const int E = in_sizes[1] / 2;
  const int Mpad = ((N + 127) / 128) * 128;
  const int* src = ei;
  const int* dst = ei + E;

  const int agg1_blocks = (N + 1) / 2;                                  // 2 nodes/block at F=256
  const int agg2_blocks = (N + 4 * AGG2_NITER - 1) / (4 * AGG2_NITER);  // 8 nodes/block

  char* ws = (char*)d_ws;
  size_t off = 0;
  auto alloc = [&](size_t bytes) -> void* {
    void* p = ws + off;
    off += (bytes + 255) & ~(size_t)255;
    return p;
  };
  int*    counts  = (int*)alloc((size_t)N * 4);        // zeroed
  int*    fill    = (int*)alloc((size_t)N * 4);        // zeroed
  size_t zero_bytes = off;
  float*  dinv    = (float*)alloc((size_t)N * 4);
  int*    row_ptr = (int*)alloc((size_t)(N + 8) * 4);
  int*    csr_src = (int*)alloc((size_t)E * 4);
  int     nb_max  = agg1_blocks > G_STATS ? agg1_blocks : G_STATS;
  double* psum    = (double*)alloc((size_t)nb_max * 8);
  double* psq     = (double*)alloc((size_t)nb_max * 8);
  double* colpart = (double*)alloc((size_t)agg2_blocks * OUT_F * 8);
  double* qpart   = (double*)alloc((size_t)agg2_blocks * 8);
  double* colsum  = (double*)alloc((size_t)(OUT_F + 1) * 8);
  float*  s0      = (float*)alloc(IN_F * 4);
  float*  t0      = (float*)alloc(IN_F * 4);
  float*  s1      = (float*)alloc(HID_F * 4);
  float*  t1      = (float*)alloc(HID_F * 4);
  u16*    Wt1     = (u16*)alloc((size_t)HID_F * IN_F * 2);
  u16*    Wt2     = (u16*)alloc((size_t)OUT_F * HID_F * 2);
  u16*    h1      = (u16*)alloc((size_t)N * HID_F * 2);     // 25.6 MB; reused for h2
  float*  c1      = (float*)alloc((size_t)N * HID_F * 4);   // 51.2 MB
  u16*    h2 = h1;     // h1 dead after agg1

  hipMemsetAsync(ws, 0, zero_bytes, stream);

  // graph prep
  count_kernel<<<1024, 256, 0, stream>>>(dst, E, counts);
  dinv_kernel<<<(N + 255) / 256, 256, 0, stream>>>(counts, dinv, N);
  scan_kernel<<<1, 1024, 0, stream>>>(counts, row_ptr, N);
  scatter_kernel<<<1024, 256, 0, stream>>>(src, dst, E, row_ptr, fill, csr_src);

  // weight transposes (bf16)
  wt_kernel<<<dim3(HID_F / 32, IN_F / 32), 256, 0, stream>>>(W1, Wt1, IN_F, HID_F);
  wt_kernel<<<dim3(OUT_F / 32, HID_F / 32), 256, 0, stream>>>(W2, Wt2, HID_F, OUT_F);

  // LN0 stats (over x) -> fused scale/shift
  stats_partial<<<G_STATS, 256, 0, stream>>>((const float4*)x, (long)N * IN_F / 4, psum, psq);
  finalize_ln<<<1, 512, 0, stream>>>(psum, psq, G_STATS, 1.0 / ((double)N * IN_F), ln0w, ln0b, s0, t0, IN_F);

  // conv1: h1 = bf16(dinv * (LN0(x) @ W1)), proven 128x128 config
  gemm_ln_mfma<2><<<dim3(Mpad / 128, HID_F / 128), 256, 0, stream>>>(x, Wt1, N, IN_F, HID_F, s0, t0, dinv, h1);
  agg_kernel<HID_F><<<agg1_blocks, 256, 0, stream>>>((const unsigned int*)h1, row_ptr, csr_src,
                                                     dinv, b1, c1, N, psum, psq);
  finalize_ln<<<1, 512, 0, stream>>>(psum, psq, agg1_blocks, 1.0 / ((double)N * HID_F), ln1w, ln1b, s1, t1, HID_F);

  // conv2: h2 = bf16(dinv * (LN1(c1) @ W2)) ; agg2 with fused column stats (no c2)
  gemm_ln_mfma<2><<<dim3(Mpad / 128, OUT_F / 128), 256, 0, stream>>>(c1, Wt2, N, HID_F, OUT_F, s1, t1, dinv, h2);
  agg_colstats<<<agg2_blocks, 256, 0, stream>>>((const unsigned int*)h2, row_ptr, csr_src,
                                                dinv, b2, N, colpart, qpart);

  // final LN + mean pool
  colred_kernel<<<OUT_F + 1, 256, 0, stream>>>(colpart, qpart, agg2_blocks, colsum);
  final_kernel<<<1, 128, 0, stream>>>(colsum, N, ln2w, ln2b, (float*)d_out);
}